// Round 10
// baseline (951.891 us; speedup 1.0000x reference)
//
#include <hip/hip_runtime.h>
#include <math.h>

#define NDIM    256
#define DMODEL  512
#define DSTATE  16
#define KLEN    14
#define DINNER  1024
#define DTRANK  32
#define BATCH   8
#define TLEN    2000
#define LOUT    497
#define MROWS   (BATCH*LOUT)   // 3976
#define NCLS    41
#define LAYERS  4
#define NCH     25
#define CSZ     20
#define TT      25             // smooth: t-outputs per thread

// per-layer weight-split region offsets (elements)
#define OFF_IP  0
#define OFF_XP  1048576
#define OFF_OP  1114112
#define SPLIT3_TOTAL 1638400

typedef __attribute__((ext_vector_type(8))) short short8;
typedef __attribute__((ext_vector_type(4))) float floatx4;

// ---------------- bf16 split helpers (RNE) ----------------
__device__ inline unsigned short bf16_rne(float f) {
    unsigned int u = __float_as_uint(f);
    u += 0x7fffu + ((u >> 16) & 1u);
    return (unsigned short)(u >> 16);
}
__device__ inline float bf16_to_f(unsigned short h) {
    return __uint_as_float(((unsigned int)h) << 16);
}
__device__ inline void write_hilo(float v, unsigned short* ph, unsigned short* pl) {
    unsigned short h = bf16_rne(v);
    *ph = h;
    *pl = bf16_rne(v - bf16_to_f(h));
}

// ---------------- native-transcendental helpers ----------------
__device__ inline float fexp(float x)  { return __expf(x); }
__device__ inline float fsilu(float x) { return x * __frcp_rn(1.f + __expf(-x)); }
__device__ inline float fsoftplus(float x) {
    return fmaxf(x, 0.f) + __logf(1.f + __expf(-fabsf(x)));
}

__device__ inline void gload16(const unsigned short* g, unsigned short* l) {
    __builtin_amdgcn_global_load_lds((const __attribute__((address_space(1))) void*)g,
                                     (__attribute__((address_space(3))) void*)l,
                                     16, 0, 0);
}

// ---------------------------------------------------------------------------
// Tiled Gaussian smoothing (sliding register window)
// ---------------------------------------------------------------------------
__global__ __launch_bounds__(256) void smooth_kernel(const float* __restrict__ X,
                                                     unsigned short* __restrict__ XSh,
                                                     unsigned short* __restrict__ XSl)
{
    int d = threadIdx.x;
    int b = blockIdx.y;
    int t0 = blockIdx.x * TT;

    float w[20]; float sum = 0.f;
    #pragma unroll
    for (int j = 0; j < 20; j++) {
        float t = ((float)j - 9.5f) * 0.5f;
        w[j] = __expf(-0.5f * t * t);
        sum += w[j];
    }
    float inv = __frcp_rn(sum);

    const float* Xb = X + ((size_t)b * TLEN) * NDIM + d;
    float win[20];
    #pragma unroll
    for (int j = 0; j < 20; j++) {
        int t2 = t0 - 9 + j;
        win[j] = (t2 >= 0 && t2 < TLEN) ? Xb[(size_t)t2 * NDIM] : 0.f;
    }
    size_t obase = ((size_t)b * TLEN + t0) * NDIM + d;
    #pragma unroll
    for (int i = 0; i < TT; i++) {
        float acc = 0.f;
        #pragma unroll
        for (int j = 0; j < 20; j++) acc = fmaf(win[j], w[j], acc);
        write_hilo(acc * inv, XSh + obase + (size_t)i * NDIM, XSl + obase + (size_t)i * NDIM);
        #pragma unroll
        for (int j = 0; j < 19; j++) win[j] = win[j + 1];
        int t2 = t0 + i + 11;
        win[19] = (t2 < TLEN) ? Xb[(size_t)t2 * NDIM] : 0.f;
    }
}

// ---------------------------------------------------------------------------
// Repack day weights for the 8 selected days (transposed, hi/lo) + bias
// ---------------------------------------------------------------------------
__global__ __launch_bounds__(256) void repack_day(const float* __restrict__ day_w,
                                                  const float* __restrict__ day_b,
                                                  const int*   __restrict__ dayIdx,
                                                  unsigned short* __restrict__ Wh,
                                                  unsigned short* __restrict__ Wl,
                                                  float* __restrict__ biasbuf)
{
    int idx = blockIdx.x * 256 + threadIdx.x;   // 8*65536
    if (idx >= 8 * 65536) return;
    int b = idx >> 16;
    int rem = idx & 65535;
    int n = rem >> 8, k = rem & 255;
    int day = dayIdx[b];
    float v = day_w[(size_t)day * 65536 + (size_t)k * 256 + n];
    write_hilo(v, Wh + idx, Wl + idx);
    if (rem < 256) biasbuf[b * 256 + rem] = day_b[(size_t)day * 256 + rem];
}

// ---------------------------------------------------------------------------
// Repack lin_in_w with K reordered as kk' = r*256 + dd (hi/lo)
// ---------------------------------------------------------------------------
__global__ __launch_bounds__(256) void repack_linin(const float* __restrict__ W,
                                                    unsigned short* __restrict__ Wh,
                                                    unsigned short* __restrict__ Wl)
{
    int idx = blockIdx.x * 256 + threadIdx.x;   // 512*3584
    if (idx >= 512 * 3584) return;
    int o = idx / 3584;
    int kk = idx - o * 3584;
    int r = kk >> 8, dd = kk & 255;
    float v = W[(size_t)o * 3584 + dd * 14 + r];
    write_hilo(v, Wh + idx, Wl + idx);
}

// ---------------------------------------------------------------------------
// Per-layer fused weight split: in_proj | x_proj | out_proj -> hi/lo scratch
// ---------------------------------------------------------------------------
__global__ __launch_bounds__(256) void split3_kernel(const float* __restrict__ ipw,
                                                     const float* __restrict__ xpw,
                                                     const float* __restrict__ opw,
                                                     unsigned short* __restrict__ Wh,
                                                     unsigned short* __restrict__ Wl)
{
    int i = blockIdx.x * 256 + threadIdx.x;
    if (i >= SPLIT3_TOTAL) return;
    float v;
    if (i < OFF_XP)      v = ipw[i];
    else if (i < OFF_OP) v = xpw[i - OFF_XP];
    else                 v = opw[i - OFF_OP];
    write_hilo(v, Wh + i, Wl + i);
}

// ---------------------------------------------------------------------------
// Generic fp32 -> bf16 hi/lo conversion (fc weights)
// ---------------------------------------------------------------------------
__global__ __launch_bounds__(256) void convw_kernel(const float* __restrict__ src,
                                                    unsigned short* __restrict__ dh,
                                                    unsigned short* __restrict__ dl,
                                                    int n)
{
    int i = blockIdx.x * 256 + threadIdx.x;
    if (i < n) write_hilo(src[i], dh + i, dl + i);
}

// ---------------------------------------------------------------------------
// Fused bf16x3 MFMA GEMM, BK=64, 96 MFMA per barrier, 4 hi/lo LDS tiles.
// ACONV=1: A operand computed on the fly = silu(conv4(xz x-half)) with in-reg
// hi/lo split and manual swizzled ds_write (deletes conv_silu + XChl buffers).
// ---------------------------------------------------------------------------
template<int WF32, int WHL, int BIASF, int ACT, int AMAP, int SPLIT, int ACONV>
__global__ __launch_bounds__(256, 2) void mfma_gemm3(
    const unsigned short* __restrict__ Ah, const unsigned short* __restrict__ Al, int lda,
    const unsigned short* __restrict__ Bh, const unsigned short* __restrict__ Bl, int ldb,
    float* __restrict__ Cf, unsigned short* __restrict__ Ch, unsigned short* __restrict__ Cl,
    int ldc, const float* __restrict__ bias, int M, int N, int K, int Kc,
    const float* __restrict__ Axz, const float* __restrict__ cw, const float* __restrict__ cb)
{
    __shared__ __align__(16) unsigned short AsH[128 * 64];
    __shared__ __align__(16) unsigned short AsL[128 * 64];
    __shared__ __align__(16) unsigned short BsH[128 * 64];
    __shared__ __align__(16) unsigned short BsL[128 * 64];
    const int tid  = threadIdx.x;
    const int wave = tid >> 6, lane = tid & 63;
    const int wm = wave & 1, wn = wave >> 1;
    const int mr = lane & 15, qh = lane >> 4;
    const int row0 = blockIdx.x * 128, col0 = blockIdx.y * 128;

    if (AMAP == 2) {
        int bb = row0 >> 11;
        Bh += (size_t)bb * 65536; Bl += (size_t)bb * 65536; bias += bb * 256;
    }

    int k0 = 0, kend = K;
    if (SPLIT) {
        k0 = blockIdx.z * Kc;
        kend = min(K, k0 + Kc);
        Cf += (size_t)blockIdx.z * (size_t)M * ldc;
    }

    // staging offsets: tile = 128 rows x 64 bf16 = 1024 chunks of 16B; 4/wave.
    size_t aoff[4], boff[4];
    int ldst[4], akk[4], arow[4], alq[4];
    #pragma unroll
    for (int i2 = 0; i2 < 4; i2++) {
        int ch = wave * 256 + i2 * 64 + lane;
        int ar = ch >> 3, ap = ch & 7;
        int ak = (ap ^ (ar & 7)) * 8;       // swizzled k offset in 64-k window
        ldst[i2] = ch * 8;                  // lane's own 16B chunk (8 shorts)
        akk[i2] = ak;
        int grow = row0 + ar;
        size_t base;
        if (AMAP == 0) {
            base = (size_t)min(grow, M - 1) * lda + ak;
        } else if (AMAP == 1) {
            int m = min(grow, M - 1);
            int b = m / 497, l = m - b * 497;
            base = ((size_t)(b * 2000 + l * 4) << 8) + ak;
        } else {
            int b = grow >> 11, t = min(grow & 2047, 1999);
            base = ((size_t)(b * 2000 + t) << 8) + ak;
        }
        aoff[i2] = base;
        if (ACONV) {
            int m = min(grow, M - 1);
            int b = m / 497;
            arow[i2] = m;
            alq[i2] = m - b * 497;          // l within batch (taps need l-j >= 0)
        }
        boff[i2] = (size_t)min(col0 + ar, N - 1) * ldb + ak;
    }

    floatx4 acc[4][4];
    #pragma unroll
    for (int i = 0; i < 4; i++)
        #pragma unroll
        for (int j = 0; j < 4; j++) acc[i][j] = (floatx4){0.f, 0.f, 0.f, 0.f};

    for (int kt = k0; kt < kend; kt += 64) {
        __syncthreads();
        if (ACONV) {
            #pragma unroll
            for (int i2 = 0; i2 < 4; i2++) {
                int c0 = kt + akk[i2];
                float a8[8];
                #pragma unroll
                for (int e = 0; e < 8; e++) a8[e] = cb[c0 + e];
                #pragma unroll
                for (int j = 0; j < 4; j++) {
                    if (alq[i2] - 3 + j >= 0) {
                        const float* rp = Axz + (size_t)(arow[i2] - 3 + j) * 2048 + c0;
                        #pragma unroll
                        for (int e = 0; e < 8; e++)
                            a8[e] = fmaf(rp[e], cw[(c0 + e) * 4 + j], a8[e]);
                    }
                }
                union { unsigned int u4[4]; short8 s8; } ph, pl2;
                #pragma unroll
                for (int e = 0; e < 4; e++) {
                    float v0 = fsilu(a8[2 * e]), v1 = fsilu(a8[2 * e + 1]);
                    unsigned short h0 = bf16_rne(v0), h1 = bf16_rne(v1);
                    unsigned short l0 = bf16_rne(v0 - bf16_to_f(h0));
                    unsigned short l1 = bf16_rne(v1 - bf16_to_f(h1));
                    ph.u4[e]  = ((unsigned int)h1 << 16) | h0;
                    pl2.u4[e] = ((unsigned int)l1 << 16) | l0;
                }
                *(short8*)&AsH[ldst[i2]] = ph.s8;
                *(short8*)&AsL[ldst[i2]] = pl2.s8;
                gload16(Bh + boff[i2] + kt, &BsH[(wave * 256 + i2 * 64) * 8]);
                gload16(Bl + boff[i2] + kt, &BsL[(wave * 256 + i2 * 64) * 8]);
            }
        } else {
            #pragma unroll
            for (int i2 = 0; i2 < 4; i2++) {
                int sb = (wave * 256 + i2 * 64) * 8;
                gload16(Ah + aoff[i2] + kt, &AsH[sb]);
                gload16(Al + aoff[i2] + kt, &AsL[sb]);
                gload16(Bh + boff[i2] + kt, &BsH[sb]);
                gload16(Bl + boff[i2] + kt, &BsL[sb]);
            }
        }
        __syncthreads();

        #pragma unroll
        for (int s = 0; s < 2; s++) {
            short8 ah4[4], al4[4], bh4[4], bl4[4];
            #pragma unroll
            for (int i = 0; i < 4; i++) {
                int ro = wm * 64 + i * 16 + mr;
                int ao = ro * 64 + (((s * 4 + qh) ^ (mr & 7)) * 8);
                ah4[i] = *(const short8*)&AsH[ao];
                al4[i] = *(const short8*)&AsL[ao];
            }
            #pragma unroll
            for (int j = 0; j < 4; j++) {
                int ro = wn * 64 + j * 16 + mr;
                int bo = ro * 64 + (((s * 4 + qh) ^ (mr & 7)) * 8);
                bh4[j] = *(const short8*)&BsH[bo];
                bl4[j] = *(const short8*)&BsL[bo];
            }
            #pragma unroll
            for (int i = 0; i < 4; i++)
                #pragma unroll
                for (int j = 0; j < 4; j++)
                    acc[i][j] = __builtin_amdgcn_mfma_f32_16x16x32_bf16(ah4[i], bh4[j], acc[i][j], 0, 0, 0);
            #pragma unroll
            for (int i = 0; i < 4; i++)
                #pragma unroll
                for (int j = 0; j < 4; j++)
                    acc[i][j] = __builtin_amdgcn_mfma_f32_16x16x32_bf16(ah4[i], bl4[j], acc[i][j], 0, 0, 0);
            #pragma unroll
            for (int i = 0; i < 4; i++)
                #pragma unroll
                for (int j = 0; j < 4; j++)
                    acc[i][j] = __builtin_amdgcn_mfma_f32_16x16x32_bf16(al4[i], bh4[j], acc[i][j], 0, 0, 0);
        }
    }

    const int rq = qh * 4;
    #pragma unroll
    for (int i = 0; i < 4; i++) {
        #pragma unroll
        for (int j = 0; j < 4; j++) {
            int colg = col0 + wn * 64 + j * 16 + mr;
            if (colg >= N) continue;
            #pragma unroll
            for (int r = 0; r < 4; r++) {
                int rowg = row0 + wm * 64 + i * 16 + rq + r;
                if (SPLIT) {
                    if (rowg < M) Cf[(size_t)rowg * ldc + colg] = acc[i][j][r];
                    continue;
                }
                int orow; bool rok;
                if (AMAP == 2) {
                    int bb = rowg >> 11, t = rowg & 2047;
                    rok = (t < 2000);
                    orow = bb * 2000 + t;
                } else { rok = (rowg < M); orow = rowg; }
                if (!rok) continue;
                float v = acc[i][j][r];
                if (BIASF) v += bias[colg];
                if (ACT == 1) v = fmaxf(v, 0.f) + log1pf(expf(-fabsf(v)));
                if (ACT == 2) v = v / (1.f + fabsf(v));
                size_t oidx = (size_t)orow * ldc + colg;
                if (WF32) Cf[oidx] = v;
                if (WHL)  write_hilo(v, Ch + oidx, Cl + oidx);
            }
        }
    }
}

// ---------------------------------------------------------------------------
// Split-K reduction + bias/act + fp32/hilo writes
// ---------------------------------------------------------------------------
template<int WF32, int WHL, int BIASF, int ACT>
__global__ __launch_bounds__(256) void reduce_k(const float* __restrict__ Cp,
                                                size_t pstride, int nsplit,
                                                float* __restrict__ Cf,
                                                unsigned short* __restrict__ Ch,
                                                unsigned short* __restrict__ Cl,
                                                const float* __restrict__ bias,
                                                int N, int total)
{
    int i = blockIdx.x * 256 + threadIdx.x;
    if (i >= total) return;
    float v = 0.f;
    for (int z = 0; z < nsplit; z++) v += Cp[(size_t)z * pstride + i];
    if (BIASF) v += bias[i % N];
    if (ACT == 1) v = fmaxf(v, 0.f) + log1pf(expf(-fabsf(v)));
    if (WF32) Cf[i] = v;
    if (WHL)  write_hilo(v, Ch + i, Cl + i);
}

// ---------------------------------------------------------------------------
// Scan phase 1: dt-dot + softplus + conv/SiLU + local scan (no DV store).
// ---------------------------------------------------------------------------
__global__ __launch_bounds__(256) void scan_part1(const float* __restrict__ XZ,
                                                  const float* __restrict__ XDBC,
                                                  const float* __restrict__ dtw,
                                                  const float* __restrict__ dtb,
                                                  const float* __restrict__ cw,
                                                  const float* __restrict__ cb,
                                                  const float* __restrict__ Alog,
                                                  float* __restrict__ SEnd,
                                                  float* __restrict__ Pp)
{
    __shared__ float sR[CSZ][64];
    int tid = threadIdx.x;
    int bid = blockIdx.x;
    int c = bid % NCH; int r = bid / NCH;
    int db = r & 3, b = r >> 2;
    int d = db * 256 + tid;
    int t0 = c * CSZ;
    int tcnt = min(CSZ, LOUT - t0);
    int rowbase = b * LOUT + t0;

    int li = tid >> 4, lj = (tid & 15) * 4;
    if (li < tcnt)
        *(float4*)&sR[li][lj] = *(const float4*)(XDBC + (size_t)(rowbase + li) * 64 + lj);
    if (li + 16 < tcnt)
        *(float4*)&sR[li + 16][lj] = *(const float4*)(XDBC + (size_t)(rowbase + li + 16) * 64 + lj);
    __syncthreads();

    float w[32];
    #pragma unroll
    for (int k = 0; k < 8; k++)
        *(float4*)&w[k * 4] = *(const float4*)(dtw + (size_t)d * 32 + k * 4);
    float dtbv = dtb[d];
    float4 cwv = *(const float4*)(cw + (size_t)d * 4);
    float cbv = cb[d];

    float a[DSTATE], cum[DSTATE], s[DSTATE];
    #pragma unroll
    for (int n = 0; n < DSTATE; n++) {
        a[n] = -fexp(Alog[(size_t)d * DSTATE + n]);
        cum[n] = 1.f; s[n] = 0.f;
    }

    const float* Xp = XZ + d;   // x half, stride 2048
    float xm1 = 0.f, xm2 = 0.f, xm3 = 0.f;
    if (t0 >= 1) xm1 = Xp[(size_t)(rowbase - 1) * 2048];
    if (t0 >= 2) xm2 = Xp[(size_t)(rowbase - 2) * 2048];
    if (t0 >= 3) xm3 = Xp[(size_t)(rowbase - 3) * 2048];
    float xr = Xp[(size_t)rowbase * 2048];

    for (int tt = 0; tt < tcnt; tt++) {
        float xr_n = (tt + 1 < tcnt) ? Xp[(size_t)(rowbase + tt + 1) * 2048] : 0.f;
        float d0 = dtbv, d1 = 0.f, d2 = 0.f, d3 = 0.f;
        #pragma unroll
        for (int k = 0; k < 8; k++) {
            d0 = fmaf(sR[tt][4*k+0], w[4*k+0], d0);
            d1 = fmaf(sR[tt][4*k+1], w[4*k+1], d1);
            d2 = fmaf(sR[tt][4*k+2], w[4*k+2], d2);
            d3 = fmaf(sR[tt][4*k+3], w[4*k+3], d3);
        }
        float dot = (d0 + d1) + (d2 + d3);
        float dv = fsoftplus(dot);
        float pre = cbv + cwv.x * xm3 + cwv.y * xm2 + cwv.z * xm1 + cwv.w * xr;
        float xv = fsilu(pre);
        float dx = dv * xv;
        #pragma unroll
        for (int n = 0; n < DSTATE; n++) {
            float e = fexp(dv * a[n]);
            cum[n] *= e;
            s[n] = fmaf(e, s[n], dx * sR[tt][32 + n]);
        }
        xm3 = xm2; xm2 = xm1; xm1 = xr; xr = xr_n;
    }
    size_t base = ((size_t)(c * 8 + b) * 16) * 1024 + d;
    #pragma unroll
    for (int n = 0; n < DSTATE; n++) {
        SEnd[base + (size_t)n * 1024] = s[n];
        Pp[base + (size_t)n * 1024]   = cum[n];
    }
}

// ---------------------------------------------------------------------------
// Scan phase 2: bulk-preloaded combine; SIn written in place over Pp.
// ---------------------------------------------------------------------------
__global__ __launch_bounds__(256) void scan_part2(const float* __restrict__ SEnd,
                                                  float* __restrict__ PS)
{
    int tid = threadIdx.x;
    int bid = blockIdx.x;           // 512 = 8b * 16n * 4db
    int db = bid & 3, n = (bid >> 2) & 15, b = bid >> 6;
    int d = db * 256 + tid;
    size_t base = ((size_t)(b * 16 + n)) * 1024 + d;
    float pc[NCH], se[NCH];
    #pragma unroll
    for (int c = 0; c < NCH; c++) {
        size_t idx = base + (size_t)c * (8 * 16 * 1024);
        pc[c] = PS[idx];
        se[c] = SEnd[idx];
    }
    float s = 0.f;
    #pragma unroll
    for (int c = 0; c < NCH; c++) {
        size_t idx = base + (size_t)c * (8 * 16 * 1024);
        PS[idx] = s;
        s = fmaf(pc[c], s, se[c]);
    }
}

// ---------------------------------------------------------------------------
// Scan phase 3: full recompute (dt-dot + conv, native ops), seeded state,
// emit gated y (hilo). No DV dependency.
// ---------------------------------------------------------------------------
__global__ __launch_bounds__(256) void scan_part3(const float* __restrict__ XZ,
                                                  const float* __restrict__ XDBC,
                                                  const float* __restrict__ dtw,
                                                  const float* __restrict__ dtb,
                                                  const float* __restrict__ cw,
                                                  const float* __restrict__ cb,
                                                  const float* __restrict__ Alog,
                                                  const float* __restrict__ Dp,
                                                  const float* __restrict__ SIn,
                                                  unsigned short* __restrict__ Yh,
                                                  unsigned short* __restrict__ Yl)
{
    __shared__ float sR[CSZ][64];
    int tid = threadIdx.x;
    int bid = blockIdx.x;
    int c = bid % NCH; int r = bid / NCH;
    int db = r & 3, b = r >> 2;
    int d = db * 256 + tid;
    int t0 = c * CSZ;
    int tcnt = min(CSZ, LOUT - t0);
    int rowbase = b * LOUT + t0;

    int li = tid >> 4, lj = (tid & 15) * 4;
    if (li < tcnt)
        *(float4*)&sR[li][lj] = *(const float4*)(XDBC + (size_t)(rowbase + li) * 64 + lj);
    if (li + 16 < tcnt)
        *(float4*)&sR[li + 16][lj] = *(const float4*)(XDBC + (size_t)(rowbase + li + 16) * 64 + lj);
    __syncthreads();

    float w[32];
    #pragma unroll
    for (int k = 0; k < 8; k++)
        *(float4*)&w[k * 4] = *(const float4*)(dtw + (size_t)d * 32 + k * 4);
    float dtbv = dtb[d];
    float4 cwv = *(const float4*)(cw + (size_t)d * 4);
    float cbv = cb[d];
    float dD = Dp[d];

    float a[DSTATE], s[DSTATE];
    size_t base = ((size_t)(c * 8 + b) * 16) * 1024 + d;
    #pragma unroll
    for (int n = 0; n < DSTATE; n++) {
        a[n] = -fexp(Alog[(size_t)d * DSTATE + n]);
        s[n] = SIn[base + (size_t)n * 1024];
    }

    const float* Xp = XZ + d;          // x half
    const float* Zp = XZ + 1024 + d;   // z half
    float xm1 = 0.f, xm2 = 0.f, xm3 = 0.f;
    if (t0 >= 1) xm1 = Xp[(size_t)(rowbase - 1) * 2048];
    if (t0 >= 2) xm2 = Xp[(size_t)(rowbase - 2) * 2048];
    if (t0 >= 3) xm3 = Xp[(size_t)(rowbase - 3) * 2048];
    float xr = Xp[(size_t)rowbase * 2048];
    float zr = Zp[(size_t)rowbase * 2048];

    for (int tt = 0; tt < tcnt; tt++) {
        float xr_n = 0.f, zr_n = 0.f;
        if (tt + 1 < tcnt) {
            xr_n = Xp[(size_t)(rowbase + tt + 1) * 2048];
            zr_n = Zp[(size_t)(rowbase + tt + 1) * 2048];
        }
        float d0 = dtbv, d1 = 0.f, d2 = 0.f, d3 = 0.f;
        #pragma unroll
        for (int k = 0; k < 8; k++) {
            d0 = fmaf(sR[tt][4*k+0], w[4*k+0], d0);
            d1 = fmaf(sR[tt][4*k+1], w[4*k+1], d1);
            d2 = fmaf(sR[tt][4*k+2], w[4*k+2], d2);
            d3 = fmaf(sR[tt][4*k+3], w[4*k+3], d3);
        }
        float dot = (d0 + d1) + (d2 + d3);
        float dv = fsoftplus(dot);
        float pre = cbv + cwv.x * xm3 + cwv.y * xm2 + cwv.z * xm1 + cwv.w * xr;
        float xv = fsilu(pre);
        float dx = dv * xv;
        float y = 0.f;
        #pragma unroll
        for (int n = 0; n < DSTATE; n++) {
            float e = fexp(dv * a[n]);
            s[n] = fmaf(e, s[n], dx * sR[tt][32 + n]);
            y = fmaf(s[n], sR[tt][48 + n], y);
        }
        float g = fsilu(zr);
        float yv = (y + xv * dD) * g;
        size_t row = (size_t)(rowbase + tt);
        write_hilo(yv, Yh + row * DINNER + d, Yl + row * DINNER + d);
        xm3 = xm2; xm2 = xm1; xm1 = xr; xr = xr_n; zr = zr_n;
    }
}

// ---------------------------------------------------------------------------
extern "C" void kernel_launch(void* const* d_in, const int* in_sizes, int n_in,
                              void* d_out, int out_size, void* d_ws, size_t ws_size,
                              hipStream_t stream)
{
    const float* neuralInput = (const float*)d_in[0];
    const int*   dayIdx      = (const int*)  d_in[1];
    const float* day_w       = (const float*)d_in[2];
    const float* day_b       = (const float*)d_in[3];
    const float* lin_in_w    = (const float*)d_in[4];
    const float* lin_in_b    = (const float*)d_in[5];
    const float* in_proj_w   = (const float*)d_in[6];
    const float* conv_w      = (const float*)d_in[7];
    const float* conv_b      = (const float*)d_in[8];
    const float* x_proj_w    = (const float*)d_in[9];
    const float* dt_w        = (const float*)d_in[10];
    const float* dt_b        = (const float*)d_in[11];
    const float* A_log       = (const float*)d_in[12];
    const float* D_param     = (const float*)d_in[13];
    const float* out_proj_w  = (const float*)d_in[14];
    const float* fc_w        = (const float*)d_in[15];
    const float* fc_b        = (const float*)d_in[16];
    float* out = (float*)d_out;

    // ---------------- workspace layout (floats) ----------------
    float* p = (float*)d_ws;
    float* xz   = p; p += (size_t)MROWS * 2048;           // 8,142,848
    float* xcv  = p; p += (size_t)MROWS * DINNER;         // 4,071,424 (Pp/SIn region)
    float* dl   = p; p += (size_t)MROWS * DINNER;         // 4,071,424 (split-K small partials)
    float* xdbc = p; p += (size_t)MROWS * 64;             //   254,464
    unsigned short* Hh = (unsigned short*)p;              // h hi/lo (3976x512)
    unsigned short* Hl = Hh + (size_t)MROWS * DMODEL;
    p += (size_t)MROWS * DMODEL;
    unsigned short* XSh = (unsigned short*)p;             // smooth out hi/lo
    unsigned short* XSl = XSh + (size_t)BATCH * TLEN * NDIM;
    p += (size_t)BATCH * TLEN * NDIM;
    float* xdreg = p;                                     // day-out region (4,096,000)
    unsigned short* XDh = (unsigned short*)p;
    unsigned short* XDl = XDh + (size_t)BATCH * TLEN * NDIM;
    p += (size_t)BATCH * TLEN * NDIM;
    unsigned short* Yh = XDh;                             // alias: scan out hi/lo
    unsigned short* Yl = Yh + (size_t)MROWS * DINNER;
    float* SEnd = xdreg;                                  // 25*8*16*1024 = 3,276,800
    float* Pp   = xcv;                                    // 3,276,800 <= 4,071,424
    float* SIn  = Pp;                                     // in-place after scan_part2
    unsigned short* Wh = (unsigned short*)p;              // weight hi/lo scratch
    unsigned short* Wl = Wh + 1835008;
    p += 1835008;                                         // 1,835,008 floats
    float* daybias = p; p += 2048;
    float* bigpart = xz;      // lin_in / out_proj split-K partials: 4 x 3976 x 512
    float* smlpart = dl;      // x_proj partials (8 x 3976 x 64); fc partials (4 x 3976 x 41)

    // 1. smooth -> XShl (tiled sliding-window)
    smooth_kernel<<<dim3(TLEN/TT, BATCH), 256, 0, stream>>>(neuralInput, XSh, XSl);
    // 2. day weights repack (hi/lo) + day GEMM (softsign) -> XDhl
    repack_day<<<dim3((8*65536)/256), 256, 0, stream>>>(day_w, day_b, dayIdx, Wh, Wl, daybias);
    mfma_gemm3<0,1,1,2,2,0,0><<<dim3(128, 2), 256, 0, stream>>>(
        XSh, XSl, 256, Wh, Wl, 256, nullptr, XDh, XDl, 256, daybias, 16000, 256, 256, 0,
        nullptr, nullptr, nullptr);
    // 3. lin_in repack (hi/lo) + split-K GEMM -> Hhl
    repack_linin<<<dim3((512*3584)/256), 256, 0, stream>>>(lin_in_w, Wh, Wl);
    mfma_gemm3<0,0,0,0,1,1,0><<<dim3(32, 4, 4), 256, 0, stream>>>(
        XDh, XDl, 0, Wh, Wl, 3584, bigpart, nullptr, nullptr, DMODEL, nullptr,
        MROWS, DMODEL, 3584, 896, nullptr, nullptr, nullptr);
    reduce_k<0,1,1,0><<<dim3((MROWS*DMODEL)/256), 256, 0, stream>>>(
        bigpart, (size_t)MROWS*DMODEL, 4, nullptr, Hh, Hl, lin_in_b, DMODEL, MROWS*DMODEL);

    for (int l = 0; l < LAYERS; l++) {
        const float* ipw = in_proj_w  + (size_t)l * 2048 * DMODEL;
        const float* cwl = conv_w     + (size_t)l * DINNER * 4;
        const float* cbl = conv_b     + (size_t)l * DINNER;
        const float* xpw = x_proj_w   + (size_t)l * 64 * DINNER;
        const float* dtw = dt_w       + (size_t)l * DINNER * DTRANK;
        const float* dtb = dt_b       + (size_t)l * DINNER;
        const float* alg = A_log      + (size_t)l * DINNER * DSTATE;
        const float* dpl = D_param    + (size_t)l * DINNER;
        const float* opw = out_proj_w + (size_t)l * DMODEL * DINNER;

        // one fused weight split per layer (in_proj | x_proj | out_proj)
        split3_kernel<<<dim3((SPLIT3_TOTAL+255)/256), 256, 0, stream>>>(ipw, xpw, opw, Wh, Wl);
        // in_proj: (3976x512)@(2048x512)^T -> xz fp32
        mfma_gemm3<1,0,0,0,0,0,0><<<dim3(32, 16), 256, 0, stream>>>(
            Hh, Hl, DMODEL, Wh + OFF_IP, Wl + OFF_IP, DMODEL, xz, nullptr, nullptr, 2048,
            nullptr, MROWS, 2048, DMODEL, 0, nullptr, nullptr, nullptr);
        // x_proj with fused conv+silu A-staging: split-K 8 -> xdbc fp32
        mfma_gemm3<0,0,0,0,0,1,1><<<dim3(32, 1, 8), 256, 0, stream>>>(
            nullptr, nullptr, DINNER, Wh + OFF_XP, Wl + OFF_XP, DINNER, smlpart, nullptr,
            nullptr, 64, nullptr, MROWS, 64, DINNER, 128, xz, cwl, cbl);
        reduce_k<1,0,0,0><<<dim3((MROWS*64)/256), 256, 0, stream>>>(
            smlpart, (size_t)MROWS*64, 8, xdbc, nullptr, nullptr, nullptr, 64, MROWS*64);
        // chunked scan (fused dt + conv + gate) -> Yhl (no DV round-trip)
        scan_part1<<<dim3(8*4*NCH), 256, 0, stream>>>(xz, xdbc, dtw, dtb, cwl, cbl, alg,
                                                      SEnd, Pp);
        scan_part2<<<dim3(512), 256, 0, stream>>>(SEnd, Pp);
        scan_part3<<<dim3(8*4*NCH), 256, 0, stream>>>(xz, xdbc, dtw, dtb, cwl, cbl, alg,
                                                      dpl, SIn, Yh, Yl);
        // out_proj: split-K 4 -> Hhl
        mfma_gemm3<0,0,0,0,0,1,0><<<dim3(32, 4, 4), 256, 0, stream>>>(
            Yh, Yl, DINNER, Wh + OFF_OP, Wl + OFF_OP, DINNER, bigpart, nullptr, nullptr,
            DMODEL, nullptr, MROWS, DMODEL, DINNER, 256, nullptr, nullptr, nullptr);
        reduce_k<0,1,0,0><<<dim3((MROWS*DMODEL)/256), 256, 0, stream>>>(
            bigpart, (size_t)MROWS*DMODEL, 4, nullptr, Hh, Hl, nullptr, DMODEL, MROWS*DMODEL);
    }

    // fc: split + split-K 4 -> out (3976 x 41) fp32 + bias
    convw_kernel<<<dim3((NCLS*DMODEL+255)/256), 256, 0, stream>>>(fc_w, Wh, Wl, NCLS*DMODEL);
    mfma_gemm3<0,0,0,0,0,1,0><<<dim3(32, 1, 4), 256, 0, stream>>>(
        Hh, Hl, DMODEL, Wh, Wl, DMODEL, smlpart, nullptr, nullptr, NCLS, nullptr,
        MROWS, NCLS, DMODEL, 128, nullptr, nullptr, nullptr);
    reduce_k<1,0,1,0><<<dim3((MROWS*NCLS+255)/256), 256, 0, stream>>>(
        smlpart, (size_t)MROWS*NCLS, 4, out, nullptr, nullptr, fc_b, NCLS, MROWS*NCLS);
}

// Round 11
// 919.072 us; speedup vs baseline: 1.0357x; 1.0357x over previous
//
#include <hip/hip_runtime.h>
#include <math.h>

#define NDIM    256
#define DMODEL  512
#define DSTATE  16
#define KLEN    14
#define DINNER  1024
#define DTRANK  32
#define BATCH   8
#define TLEN    2000
#define LOUT    497
#define MROWS   (BATCH*LOUT)   // 3976
#define NCLS    41
#define LAYERS  4
#define NCH     25
#define CSZ     20
#define TT      25             // smooth: t-outputs per thread

// per-layer weight-split region offsets (elements)
#define OFF_IP  0
#define OFF_XP  1048576
#define OFF_OP  1114112
#define SPLIT3_TOTAL 1638400

typedef __attribute__((ext_vector_type(8))) short short8;
typedef __attribute__((ext_vector_type(4))) float floatx4;

// ---------------- bf16 split helpers (RNE) ----------------
__device__ inline unsigned short bf16_rne(float f) {
    unsigned int u = __float_as_uint(f);
    u += 0x7fffu + ((u >> 16) & 1u);
    return (unsigned short)(u >> 16);
}
__device__ inline float bf16_to_f(unsigned short h) {
    return __uint_as_float(((unsigned int)h) << 16);
}
__device__ inline void write_hilo(float v, unsigned short* ph, unsigned short* pl) {
    unsigned short h = bf16_rne(v);
    *ph = h;
    *pl = bf16_rne(v - bf16_to_f(h));
}

// ---------------- native-transcendental helpers ----------------
__device__ inline float fexp(float x)  { return __expf(x); }
__device__ inline float fsilu(float x) { return x * __frcp_rn(1.f + __expf(-x)); }
__device__ inline float fsoftplus(float x) {
    return fmaxf(x, 0.f) + __logf(1.f + __expf(-fabsf(x)));
}

__device__ inline void gload16(const unsigned short* g, unsigned short* l) {
    __builtin_amdgcn_global_load_lds((const __attribute__((address_space(1))) void*)g,
                                     (__attribute__((address_space(3))) void*)l,
                                     16, 0, 0);
}

// ---------------------------------------------------------------------------
// Tiled Gaussian smoothing (sliding register window)
// ---------------------------------------------------------------------------
__global__ __launch_bounds__(256) void smooth_kernel(const float* __restrict__ X,
                                                     unsigned short* __restrict__ XSh,
                                                     unsigned short* __restrict__ XSl)
{
    int d = threadIdx.x;
    int b = blockIdx.y;
    int t0 = blockIdx.x * TT;

    float w[20]; float sum = 0.f;
    #pragma unroll
    for (int j = 0; j < 20; j++) {
        float t = ((float)j - 9.5f) * 0.5f;
        w[j] = __expf(-0.5f * t * t);
        sum += w[j];
    }
    float inv = __frcp_rn(sum);

    const float* Xb = X + ((size_t)b * TLEN) * NDIM + d;
    float win[20];
    #pragma unroll
    for (int j = 0; j < 20; j++) {
        int t2 = t0 - 9 + j;
        win[j] = (t2 >= 0 && t2 < TLEN) ? Xb[(size_t)t2 * NDIM] : 0.f;
    }
    size_t obase = ((size_t)b * TLEN + t0) * NDIM + d;
    #pragma unroll
    for (int i = 0; i < TT; i++) {
        float acc = 0.f;
        #pragma unroll
        for (int j = 0; j < 20; j++) acc = fmaf(win[j], w[j], acc);
        write_hilo(acc * inv, XSh + obase + (size_t)i * NDIM, XSl + obase + (size_t)i * NDIM);
        #pragma unroll
        for (int j = 0; j < 19; j++) win[j] = win[j + 1];
        int t2 = t0 + i + 11;
        win[19] = (t2 < TLEN) ? Xb[(size_t)t2 * NDIM] : 0.f;
    }
}

// ---------------------------------------------------------------------------
// Repack day weights for the 8 selected days (transposed, hi/lo) + bias
// ---------------------------------------------------------------------------
__global__ __launch_bounds__(256) void repack_day(const float* __restrict__ day_w,
                                                  const float* __restrict__ day_b,
                                                  const int*   __restrict__ dayIdx,
                                                  unsigned short* __restrict__ Wh,
                                                  unsigned short* __restrict__ Wl,
                                                  float* __restrict__ biasbuf)
{
    int idx = blockIdx.x * 256 + threadIdx.x;   // 8*65536
    if (idx >= 8 * 65536) return;
    int b = idx >> 16;
    int rem = idx & 65535;
    int n = rem >> 8, k = rem & 255;
    int day = dayIdx[b];
    float v = day_w[(size_t)day * 65536 + (size_t)k * 256 + n];
    write_hilo(v, Wh + idx, Wl + idx);
    if (rem < 256) biasbuf[b * 256 + rem] = day_b[(size_t)day * 256 + rem];
}

// ---------------------------------------------------------------------------
// Repack lin_in_w with K reordered as kk' = r*256 + dd (hi/lo)
// ---------------------------------------------------------------------------
__global__ __launch_bounds__(256) void repack_linin(const float* __restrict__ W,
                                                    unsigned short* __restrict__ Wh,
                                                    unsigned short* __restrict__ Wl)
{
    int idx = blockIdx.x * 256 + threadIdx.x;   // 512*3584
    if (idx >= 512 * 3584) return;
    int o = idx / 3584;
    int kk = idx - o * 3584;
    int r = kk >> 8, dd = kk & 255;
    float v = W[(size_t)o * 3584 + dd * 14 + r];
    write_hilo(v, Wh + idx, Wl + idx);
}

// ---------------------------------------------------------------------------
// Per-layer fused weight split: in_proj | x_proj | out_proj -> hi/lo scratch
// ---------------------------------------------------------------------------
__global__ __launch_bounds__(256) void split3_kernel(const float* __restrict__ ipw,
                                                     const float* __restrict__ xpw,
                                                     const float* __restrict__ opw,
                                                     unsigned short* __restrict__ Wh,
                                                     unsigned short* __restrict__ Wl)
{
    int i = blockIdx.x * 256 + threadIdx.x;
    if (i >= SPLIT3_TOTAL) return;
    float v;
    if (i < OFF_XP)      v = ipw[i];
    else if (i < OFF_OP) v = xpw[i - OFF_XP];
    else                 v = opw[i - OFF_OP];
    write_hilo(v, Wh + i, Wl + i);
}

// ---------------------------------------------------------------------------
// Generic fp32 -> bf16 hi/lo conversion (fc weights)
// ---------------------------------------------------------------------------
__global__ __launch_bounds__(256) void convw_kernel(const float* __restrict__ src,
                                                    unsigned short* __restrict__ dh,
                                                    unsigned short* __restrict__ dl,
                                                    int n)
{
    int i = blockIdx.x * 256 + threadIdx.x;
    if (i < n) write_hilo(src[i], dh + i, dl + i);
}

// ---------------------------------------------------------------------------
// Fused bf16x3 MFMA GEMM, BK=64, 96 MFMA per barrier, 4 hi/lo LDS tiles.
// LDS 64KB (4 x 16KB). XOR swizzle (chunk ^ row&7) — measured 0 conflicts.
// ---------------------------------------------------------------------------
template<int WF32, int WHL, int BIASF, int ACT, int AMAP, int SPLIT>
__global__ __launch_bounds__(256, 2) void mfma_gemm3(
    const unsigned short* __restrict__ Ah, const unsigned short* __restrict__ Al, int lda,
    const unsigned short* __restrict__ Bh, const unsigned short* __restrict__ Bl, int ldb,
    float* __restrict__ Cf, unsigned short* __restrict__ Ch, unsigned short* __restrict__ Cl,
    int ldc, const float* __restrict__ bias, int M, int N, int K, int Kc)
{
    __shared__ __align__(16) unsigned short AsH[128 * 64];
    __shared__ __align__(16) unsigned short AsL[128 * 64];
    __shared__ __align__(16) unsigned short BsH[128 * 64];
    __shared__ __align__(16) unsigned short BsL[128 * 64];
    const int tid  = threadIdx.x;
    const int wave = tid >> 6, lane = tid & 63;
    const int wm = wave & 1, wn = wave >> 1;
    const int mr = lane & 15, qh = lane >> 4;
    const int row0 = blockIdx.x * 128, col0 = blockIdx.y * 128;

    if (AMAP == 2) {
        int bb = row0 >> 11;
        Bh += (size_t)bb * 65536; Bl += (size_t)bb * 65536; bias += bb * 256;
    }

    int k0 = 0, kend = K;
    if (SPLIT) {
        k0 = blockIdx.z * Kc;
        kend = min(K, k0 + Kc);
        Cf += (size_t)blockIdx.z * (size_t)M * ldc;
    }

    // staging offsets: tile = 128 rows x 64 bf16 = 1024 chunks of 16B; 4/wave.
    size_t aoff[4], boff[4];
    int ldst[4];
    #pragma unroll
    for (int i2 = 0; i2 < 4; i2++) {
        int ch = wave * 256 + i2 * 64 + lane;
        int ar = ch >> 3, ap = ch & 7;
        int ak = (ap ^ (ar & 7)) * 8;       // swizzled bf16 offset in 64-k window
        ldst[i2] = ch * 8;
        int grow = row0 + ar;
        size_t base;
        if (AMAP == 0) {
            base = (size_t)min(grow, M - 1) * lda + ak;
        } else if (AMAP == 1) {
            int m = min(grow, M - 1);
            int b = m / 497, l = m - b * 497;
            base = ((size_t)(b * 2000 + l * 4) << 8) + ak;
        } else {
            int b = grow >> 11, t = min(grow & 2047, 1999);
            base = ((size_t)(b * 2000 + t) << 8) + ak;
        }
        aoff[i2] = base;
        boff[i2] = (size_t)min(col0 + ar, N - 1) * ldb + ak;
    }

    floatx4 acc[4][4];
    #pragma unroll
    for (int i = 0; i < 4; i++)
        #pragma unroll
        for (int j = 0; j < 4; j++) acc[i][j] = (floatx4){0.f, 0.f, 0.f, 0.f};

    for (int kt = k0; kt < kend; kt += 64) {
        __syncthreads();
        #pragma unroll
        for (int i2 = 0; i2 < 4; i2++) {
            gload16(Ah + aoff[i2] + kt, &AsH[ldst[i2]]);
            gload16(Al + aoff[i2] + kt, &AsL[ldst[i2]]);
            gload16(Bh + boff[i2] + kt, &BsH[ldst[i2]]);
            gload16(Bl + boff[i2] + kt, &BsL[ldst[i2]]);
        }
        __syncthreads();

        #pragma unroll
        for (int s = 0; s < 2; s++) {
            short8 ah4[4], al4[4], bh4[4], bl4[4];
            #pragma unroll
            for (int i = 0; i < 4; i++) {
                int ro = wm * 64 + i * 16 + mr;
                int ao = ro * 64 + (((s * 4 + qh) ^ (mr & 7)) * 8);
                ah4[i] = *(const short8*)&AsH[ao];
                al4[i] = *(const short8*)&AsL[ao];
            }
            #pragma unroll
            for (int j = 0; j < 4; j++) {
                int ro = wn * 64 + j * 16 + mr;
                int bo = ro * 64 + (((s * 4 + qh) ^ (mr & 7)) * 8);
                bh4[j] = *(const short8*)&BsH[bo];
                bl4[j] = *(const short8*)&BsL[bo];
            }
            #pragma unroll
            for (int i = 0; i < 4; i++)
                #pragma unroll
                for (int j = 0; j < 4; j++)
                    acc[i][j] = __builtin_amdgcn_mfma_f32_16x16x32_bf16(ah4[i], bh4[j], acc[i][j], 0, 0, 0);
            #pragma unroll
            for (int i = 0; i < 4; i++)
                #pragma unroll
                for (int j = 0; j < 4; j++)
                    acc[i][j] = __builtin_amdgcn_mfma_f32_16x16x32_bf16(ah4[i], bl4[j], acc[i][j], 0, 0, 0);
            #pragma unroll
            for (int i = 0; i < 4; i++)
                #pragma unroll
                for (int j = 0; j < 4; j++)
                    acc[i][j] = __builtin_amdgcn_mfma_f32_16x16x32_bf16(al4[i], bh4[j], acc[i][j], 0, 0, 0);
        }
    }

    const int rq = qh * 4;
    #pragma unroll
    for (int i = 0; i < 4; i++) {
        #pragma unroll
        for (int j = 0; j < 4; j++) {
            int colg = col0 + wn * 64 + j * 16 + mr;
            if (colg >= N) continue;
            #pragma unroll
            for (int r = 0; r < 4; r++) {
                int rowg = row0 + wm * 64 + i * 16 + rq + r;
                if (SPLIT) {
                    if (rowg < M) Cf[(size_t)rowg * ldc + colg] = acc[i][j][r];
                    continue;
                }
                int orow; bool rok;
                if (AMAP == 2) {
                    int bb = rowg >> 11, t = rowg & 2047;
                    rok = (t < 2000);
                    orow = bb * 2000 + t;
                } else { rok = (rowg < M); orow = rowg; }
                if (!rok) continue;
                float v = acc[i][j][r];
                if (BIASF) v += bias[colg];
                if (ACT == 1) v = fmaxf(v, 0.f) + log1pf(expf(-fabsf(v)));
                if (ACT == 2) v = v / (1.f + fabsf(v));
                size_t oidx = (size_t)orow * ldc + colg;
                if (WF32) Cf[oidx] = v;
                if (WHL)  write_hilo(v, Ch + oidx, Cl + oidx);
            }
        }
    }
}

// ---------------------------------------------------------------------------
// Split-K reduction + bias/act + fp32/hilo writes
// ---------------------------------------------------------------------------
template<int WF32, int WHL, int BIASF, int ACT>
__global__ __launch_bounds__(256) void reduce_k(const float* __restrict__ Cp,
                                                size_t pstride, int nsplit,
                                                float* __restrict__ Cf,
                                                unsigned short* __restrict__ Ch,
                                                unsigned short* __restrict__ Cl,
                                                const float* __restrict__ bias,
                                                int N, int total)
{
    int i = blockIdx.x * 256 + threadIdx.x;
    if (i >= total) return;
    float v = 0.f;
    for (int z = 0; z < nsplit; z++) v += Cp[(size_t)z * pstride + i];
    if (BIASF) v += bias[i % N];
    if (ACT == 1) v = fmaxf(v, 0.f) + log1pf(expf(-fabsf(v)));
    if (WF32) Cf[i] = v;
    if (WHL)  write_hilo(v, Ch + i, Cl + i);
}

// ---------------------------------------------------------------------------
// Causal depthwise conv (k=4) + bias + SiLU -> hi/lo only (x_proj A operand)
// ---------------------------------------------------------------------------
__global__ __launch_bounds__(256) void conv_silu_kernel(const float* __restrict__ XZ,
                                                        const float* __restrict__ cw,
                                                        const float* __restrict__ cb,
                                                        unsigned short* __restrict__ XCh,
                                                        unsigned short* __restrict__ XCl)
{
    int idx = blockIdx.x * 256 + threadIdx.x;   // 3976*1024
    if (idx >= MROWS * DINNER) return;
    int row = idx >> 10, c = idx & 1023;
    unsigned b = (unsigned)row / 497u;
    int l = row - (int)b * 497;
    float acc = cb[c];
    #pragma unroll
    for (int j = 0; j < 4; j++) {
        int lj = l - 3 + j;
        if (lj >= 0) acc += XZ[(size_t)(row - 3 + j) * 2048 + c] * cw[c * 4 + j];
    }
    write_hilo(fsilu(acc), XCh + idx, XCl + idx);
}

// ---------------------------------------------------------------------------
// Scan phase 1: dt-dot + softplus + conv/SiLU + local scan (no DV store).
// ---------------------------------------------------------------------------
__global__ __launch_bounds__(256) void scan_part1(const float* __restrict__ XZ,
                                                  const float* __restrict__ XDBC,
                                                  const float* __restrict__ dtw,
                                                  const float* __restrict__ dtb,
                                                  const float* __restrict__ cw,
                                                  const float* __restrict__ cb,
                                                  const float* __restrict__ Alog,
                                                  float* __restrict__ SEnd,
                                                  float* __restrict__ Pp)
{
    __shared__ float sR[CSZ][64];
    int tid = threadIdx.x;
    int bid = blockIdx.x;
    int c = bid % NCH; int r = bid / NCH;
    int db = r & 3, b = r >> 2;
    int d = db * 256 + tid;
    int t0 = c * CSZ;
    int tcnt = min(CSZ, LOUT - t0);
    int rowbase = b * LOUT + t0;

    int li = tid >> 4, lj = (tid & 15) * 4;
    if (li < tcnt)
        *(float4*)&sR[li][lj] = *(const float4*)(XDBC + (size_t)(rowbase + li) * 64 + lj);
    if (li + 16 < tcnt)
        *(float4*)&sR[li + 16][lj] = *(const float4*)(XDBC + (size_t)(rowbase + li + 16) * 64 + lj);
    __syncthreads();

    float w[32];
    #pragma unroll
    for (int k = 0; k < 8; k++)
        *(float4*)&w[k * 4] = *(const float4*)(dtw + (size_t)d * 32 + k * 4);
    float dtbv = dtb[d];
    float4 cwv = *(const float4*)(cw + (size_t)d * 4);
    float cbv = cb[d];

    float a[DSTATE], cum[DSTATE], s[DSTATE];
    #pragma unroll
    for (int n = 0; n < DSTATE; n++) {
        a[n] = -fexp(Alog[(size_t)d * DSTATE + n]);
        cum[n] = 1.f; s[n] = 0.f;
    }

    const float* Xp = XZ + d;   // x half, stride 2048
    float xm1 = 0.f, xm2 = 0.f, xm3 = 0.f;
    if (t0 >= 1) xm1 = Xp[(size_t)(rowbase - 1) * 2048];
    if (t0 >= 2) xm2 = Xp[(size_t)(rowbase - 2) * 2048];
    if (t0 >= 3) xm3 = Xp[(size_t)(rowbase - 3) * 2048];
    float xr = Xp[(size_t)rowbase * 2048];

    for (int tt = 0; tt < tcnt; tt++) {
        float xr_n = (tt + 1 < tcnt) ? Xp[(size_t)(rowbase + tt + 1) * 2048] : 0.f;
        float d0 = dtbv, d1 = 0.f, d2 = 0.f, d3 = 0.f;
        #pragma unroll
        for (int k = 0; k < 8; k++) {
            d0 = fmaf(sR[tt][4*k+0], w[4*k+0], d0);
            d1 = fmaf(sR[tt][4*k+1], w[4*k+1], d1);
            d2 = fmaf(sR[tt][4*k+2], w[4*k+2], d2);
            d3 = fmaf(sR[tt][4*k+3], w[4*k+3], d3);
        }
        float dot = (d0 + d1) + (d2 + d3);
        float dv = fsoftplus(dot);
        float pre = cbv + cwv.x * xm3 + cwv.y * xm2 + cwv.z * xm1 + cwv.w * xr;
        float xv = fsilu(pre);
        float dx = dv * xv;
        #pragma unroll
        for (int n = 0; n < DSTATE; n++) {
            float e = fexp(dv * a[n]);
            cum[n] *= e;
            s[n] = fmaf(e, s[n], dx * sR[tt][32 + n]);
        }
        xm3 = xm2; xm2 = xm1; xm1 = xr; xr = xr_n;
    }
    size_t base = ((size_t)(c * 8 + b) * 16) * 1024 + d;
    #pragma unroll
    for (int n = 0; n < DSTATE; n++) {
        SEnd[base + (size_t)n * 1024] = s[n];
        Pp[base + (size_t)n * 1024]   = cum[n];
    }
}

// ---------------------------------------------------------------------------
// Scan phase 2: bulk-preloaded combine; SIn written in place over Pp.
// ---------------------------------------------------------------------------
__global__ __launch_bounds__(256) void scan_part2(const float* __restrict__ SEnd,
                                                  float* __restrict__ PS)
{
    int tid = threadIdx.x;
    int bid = blockIdx.x;           // 512 = 8b * 16n * 4db
    int db = bid & 3, n = (bid >> 2) & 15, b = bid >> 6;
    int d = db * 256 + tid;
    size_t base = ((size_t)(b * 16 + n)) * 1024 + d;
    float pc[NCH], se[NCH];
    #pragma unroll
    for (int c = 0; c < NCH; c++) {
        size_t idx = base + (size_t)c * (8 * 16 * 1024);
        pc[c] = PS[idx];
        se[c] = SEnd[idx];
    }
    float s = 0.f;
    #pragma unroll
    for (int c = 0; c < NCH; c++) {
        size_t idx = base + (size_t)c * (8 * 16 * 1024);
        PS[idx] = s;
        s = fmaf(pc[c], s, se[c]);
    }
}

// ---------------------------------------------------------------------------
// Scan phase 3: full recompute (dt-dot + conv, native ops), seeded state,
// emit gated y (hilo). No DV dependency.
// ---------------------------------------------------------------------------
__global__ __launch_bounds__(256) void scan_part3(const float* __restrict__ XZ,
                                                  const float* __restrict__ XDBC,
                                                  const float* __restrict__ dtw,
                                                  const float* __restrict__ dtb,
                                                  const float* __restrict__ cw,
                                                  const float* __restrict__ cb,
                                                  const float* __restrict__ Alog,
                                                  const float* __restrict__ Dp,
                                                  const float* __restrict__ SIn,
                                                  unsigned short* __restrict__ Yh,
                                                  unsigned short* __restrict__ Yl)
{
    __shared__ float sR[CSZ][64];
    int tid = threadIdx.x;
    int bid = blockIdx.x;
    int c = bid % NCH; int r = bid / NCH;
    int db = r & 3, b = r >> 2;
    int d = db * 256 + tid;
    int t0 = c * CSZ;
    int tcnt = min(CSZ, LOUT - t0);
    int rowbase = b * LOUT + t0;

    int li = tid >> 4, lj = (tid & 15) * 4;
    if (li < tcnt)
        *(float4*)&sR[li][lj] = *(const float4*)(XDBC + (size_t)(rowbase + li) * 64 + lj);
    if (li + 16 < tcnt)
        *(float4*)&sR[li + 16][lj] = *(const float4*)(XDBC + (size_t)(rowbase + li + 16) * 64 + lj);
    __syncthreads();

    float w[32];
    #pragma unroll
    for (int k = 0; k < 8; k++)
        *(float4*)&w[k * 4] = *(const float4*)(dtw + (size_t)d * 32 + k * 4);
    float dtbv = dtb[d];
    float4 cwv = *(const float4*)(cw + (size_t)d * 4);
    float cbv = cb[d];
    float dD = Dp[d];

    float a[DSTATE], s[DSTATE];
    size_t base = ((size_t)(c * 8 + b) * 16) * 1024 + d;
    #pragma unroll
    for (int n = 0; n < DSTATE; n++) {
        a[n] = -fexp(Alog[(size_t)d * DSTATE + n]);
        s[n] = SIn[base + (size_t)n * 1024];
    }

    const float* Xp = XZ + d;          // x half
    const float* Zp = XZ + 1024 + d;   // z half
    float xm1 = 0.f, xm2 = 0.f, xm3 = 0.f;
    if (t0 >= 1) xm1 = Xp[(size_t)(rowbase - 1) * 2048];
    if (t0 >= 2) xm2 = Xp[(size_t)(rowbase - 2) * 2048];
    if (t0 >= 3) xm3 = Xp[(size_t)(rowbase - 3) * 2048];
    float xr = Xp[(size_t)rowbase * 2048];
    float zr = Zp[(size_t)rowbase * 2048];

    for (int tt = 0; tt < tcnt; tt++) {
        float xr_n = 0.f, zr_n = 0.f;
        if (tt + 1 < tcnt) {
            xr_n = Xp[(size_t)(rowbase + tt + 1) * 2048];
            zr_n = Zp[(size_t)(rowbase + tt + 1) * 2048];
        }
        float d0 = dtbv, d1 = 0.f, d2 = 0.f, d3 = 0.f;
        #pragma unroll
        for (int k = 0; k < 8; k++) {
            d0 = fmaf(sR[tt][4*k+0], w[4*k+0], d0);
            d1 = fmaf(sR[tt][4*k+1], w[4*k+1], d1);
            d2 = fmaf(sR[tt][4*k+2], w[4*k+2], d2);
            d3 = fmaf(sR[tt][4*k+3], w[4*k+3], d3);
        }
        float dot = (d0 + d1) + (d2 + d3);
        float dv = fsoftplus(dot);
        float pre = cbv + cwv.x * xm3 + cwv.y * xm2 + cwv.z * xm1 + cwv.w * xr;
        float xv = fsilu(pre);
        float dx = dv * xv;
        float y = 0.f;
        #pragma unroll
        for (int n = 0; n < DSTATE; n++) {
            float e = fexp(dv * a[n]);
            s[n] = fmaf(e, s[n], dx * sR[tt][32 + n]);
            y = fmaf(s[n], sR[tt][48 + n], y);
        }
        float g = fsilu(zr);
        float yv = (y + xv * dD) * g;
        size_t row = (size_t)(rowbase + tt);
        write_hilo(yv, Yh + row * DINNER + d, Yl + row * DINNER + d);
        xm3 = xm2; xm2 = xm1; xm1 = xr; xr = xr_n; zr = zr_n;
    }
}

// ---------------------------------------------------------------------------
extern "C" void kernel_launch(void* const* d_in, const int* in_sizes, int n_in,
                              void* d_out, int out_size, void* d_ws, size_t ws_size,
                              hipStream_t stream)
{
    const float* neuralInput = (const float*)d_in[0];
    const int*   dayIdx      = (const int*)  d_in[1];
    const float* day_w       = (const float*)d_in[2];
    const float* day_b       = (const float*)d_in[3];
    const float* lin_in_w    = (const float*)d_in[4];
    const float* lin_in_b    = (const float*)d_in[5];
    const float* in_proj_w   = (const float*)d_in[6];
    const float* conv_w      = (const float*)d_in[7];
    const float* conv_b      = (const float*)d_in[8];
    const float* x_proj_w    = (const float*)d_in[9];
    const float* dt_w        = (const float*)d_in[10];
    const float* dt_b        = (const float*)d_in[11];
    const float* A_log       = (const float*)d_in[12];
    const float* D_param     = (const float*)d_in[13];
    const float* out_proj_w  = (const float*)d_in[14];
    const float* fc_w        = (const float*)d_in[15];
    const float* fc_b        = (const float*)d_in[16];
    float* out = (float*)d_out;

    // ---------------- workspace layout (floats) ----------------
    float* p = (float*)d_ws;
    float* xz   = p; p += (size_t)MROWS * 2048;           // 8,142,848
    float* xcv  = p; p += (size_t)MROWS * DINNER;         // 4,071,424 (Pp/SIn region)
    float* dl   = p; p += (size_t)MROWS * DINNER;         // 4,071,424 (split-K small partials)
    float* xdbc = p; p += (size_t)MROWS * 64;             //   254,464
    unsigned short* Hh = (unsigned short*)p;              // h hi/lo (3976x512)
    unsigned short* Hl = Hh + (size_t)MROWS * DMODEL;
    p += (size_t)MROWS * DMODEL;
    unsigned short* XSh = (unsigned short*)p;             // smooth out hi/lo
    unsigned short* XSl = XSh + (size_t)BATCH * TLEN * NDIM;
    p += (size_t)BATCH * TLEN * NDIM;
    unsigned short* XCh = XSh;                            // alias: conv out hi/lo
    unsigned short* XCl = XCh + (size_t)MROWS * DINNER;
    float* xdreg = p;                                     // day-out region (4,096,000)
    unsigned short* XDh = (unsigned short*)p;
    unsigned short* XDl = XDh + (size_t)BATCH * TLEN * NDIM;
    p += (size_t)BATCH * TLEN * NDIM;
    unsigned short* Yh = XDh;                             // alias: scan out hi/lo
    unsigned short* Yl = Yh + (size_t)MROWS * DINNER;
    float* SEnd = xdreg;                                  // 25*8*16*1024 = 3,276,800
    float* Pp   = xcv;                                    // 3,276,800 <= 4,071,424
    float* SIn  = Pp;                                     // in-place after scan_part2
    unsigned short* Wh = (unsigned short*)p;              // weight hi/lo scratch
    unsigned short* Wl = Wh + 1835008;
    p += 1835008;                                         // 1,835,008 floats
    float* daybias = p; p += 2048;
    float* bigpart = xz;      // lin_in / out_proj split-K partials: 4 x 3976 x 512
    float* smlpart = dl;      // x_proj partials (8 x 3976 x 64); fc partials (4 x 3976 x 41)

    // 1. smooth -> XShl (tiled sliding-window)
    smooth_kernel<<<dim3(TLEN/TT, BATCH), 256, 0, stream>>>(neuralInput, XSh, XSl);
    // 2. day weights repack (hi/lo) + day GEMM (softsign) -> XDhl
    repack_day<<<dim3((8*65536)/256), 256, 0, stream>>>(day_w, day_b, dayIdx, Wh, Wl, daybias);
    mfma_gemm3<0,1,1,2,2,0><<<dim3(128, 2), 256, 0, stream>>>(
        XSh, XSl, 256, Wh, Wl, 256, nullptr, XDh, XDl, 256, daybias, 16000, 256, 256, 0);
    // 3. lin_in repack (hi/lo) + split-K GEMM -> Hhl
    repack_linin<<<dim3((512*3584)/256), 256, 0, stream>>>(lin_in_w, Wh, Wl);
    mfma_gemm3<0,0,0,0,1,1><<<dim3(32, 4, 4), 256, 0, stream>>>(
        XDh, XDl, 0, Wh, Wl, 3584, bigpart, nullptr, nullptr, DMODEL, nullptr,
        MROWS, DMODEL, 3584, 896);
    reduce_k<0,1,1,0><<<dim3((MROWS*DMODEL)/256), 256, 0, stream>>>(
        bigpart, (size_t)MROWS*DMODEL, 4, nullptr, Hh, Hl, lin_in_b, DMODEL, MROWS*DMODEL);

    for (int l = 0; l < LAYERS; l++) {
        const float* ipw = in_proj_w  + (size_t)l * 2048 * DMODEL;
        const float* cwl = conv_w     + (size_t)l * DINNER * 4;
        const float* cbl = conv_b     + (size_t)l * DINNER;
        const float* xpw = x_proj_w   + (size_t)l * 64 * DINNER;
        const float* dtw = dt_w       + (size_t)l * DINNER * DTRANK;
        const float* dtb = dt_b       + (size_t)l * DINNER;
        const float* alg = A_log      + (size_t)l * DINNER * DSTATE;
        const float* dpl = D_param    + (size_t)l * DINNER;
        const float* opw = out_proj_w + (size_t)l * DMODEL * DINNER;

        // one fused weight split per layer (in_proj | x_proj | out_proj)
        split3_kernel<<<dim3((SPLIT3_TOTAL+255)/256), 256, 0, stream>>>(ipw, xpw, opw, Wh, Wl);
        // in_proj: (3976x512)@(2048x512)^T -> xz fp32
        mfma_gemm3<1,0,0,0,0,0><<<dim3(32, 16), 256, 0, stream>>>(
            Hh, Hl, DMODEL, Wh + OFF_IP, Wl + OFF_IP, DMODEL, xz, nullptr, nullptr, 2048,
            nullptr, MROWS, 2048, DMODEL, 0);
        // conv + silu -> XChl (hilo only)
        conv_silu_kernel<<<dim3((MROWS*DINNER)/256), 256, 0, stream>>>(xz, cwl, cbl, XCh, XCl);
        // x_proj: split-K 8 -> xdbc fp32
        mfma_gemm3<0,0,0,0,0,1><<<dim3(32, 1, 8), 256, 0, stream>>>(
            XCh, XCl, DINNER, Wh + OFF_XP, Wl + OFF_XP, DINNER, smlpart, nullptr, nullptr, 64,
            nullptr, MROWS, 64, DINNER, 128);
        reduce_k<1,0,0,0><<<dim3((MROWS*64)/256), 256, 0, stream>>>(
            smlpart, (size_t)MROWS*64, 8, xdbc, nullptr, nullptr, nullptr, 64, MROWS*64);
        // chunked scan (fused dt + conv + gate) -> Yhl (no DV round-trip)
        scan_part1<<<dim3(8*4*NCH), 256, 0, stream>>>(xz, xdbc, dtw, dtb, cwl, cbl, alg,
                                                      SEnd, Pp);
        scan_part2<<<dim3(512), 256, 0, stream>>>(SEnd, Pp);
        scan_part3<<<dim3(8*4*NCH), 256, 0, stream>>>(xz, xdbc, dtw, dtb, cwl, cbl, alg,
                                                      dpl, SIn, Yh, Yl);
        // out_proj: split-K 4 -> Hhl
        mfma_gemm3<0,0,0,0,0,1><<<dim3(32, 4, 4), 256, 0, stream>>>(
            Yh, Yl, DINNER, Wh + OFF_OP, Wl + OFF_OP, DINNER, bigpart, nullptr, nullptr,
            DMODEL, nullptr, MROWS, DMODEL, DINNER, 256);
        reduce_k<0,1,0,0><<<dim3((MROWS*DMODEL)/256), 256, 0, stream>>>(
            bigpart, (size_t)MROWS*DMODEL, 4, nullptr, Hh, Hl, nullptr, DMODEL, MROWS*DMODEL);
    }

    // fc: split + split-K 4 -> out (3976 x 41) fp32 + bias
    convw_kernel<<<dim3((NCLS*DMODEL+255)/256), 256, 0, stream>>>(fc_w, Wh, Wl, NCLS*DMODEL);
    mfma_gemm3<0,0,0,0,0,1><<<dim3(32, 1, 4), 256, 0, stream>>>(
        Hh, Hl, DMODEL, Wh, Wl, DMODEL, smlpart, nullptr, nullptr, NCLS, nullptr,
        MROWS, NCLS, DMODEL, 128);
    reduce_k<1,0,1,0><<<dim3((MROWS*NCLS+255)/256), 256, 0, stream>>>(
        smlpart, (size_t)MROWS*NCLS, 4, out, nullptr, nullptr, fc_b, NCLS, MROWS*NCLS);
}

// Round 12
// 869.174 us; speedup vs baseline: 1.0952x; 1.0574x over previous
//
#include <hip/hip_runtime.h>
#include <math.h>

#define NDIM    256
#define DMODEL  512
#define DSTATE  16
#define KLEN    14
#define DINNER  1024
#define DTRANK  32
#define BATCH   8
#define TLEN    2000
#define LOUT    497
#define MROWS   (BATCH*LOUT)   // 3976
#define NCLS    41
#define LAYERS  4
#define NCH     25
#define CSZ     20
#define TT      25             // smooth: t-outputs per thread
#define PSTRIDE (MROWS*64)     // x_proj split-K partial stride

// per-layer weight-split region offsets (elements)
#define OFF_IP  0
#define OFF_XP  1048576
#define OFF_OP  1114112
#define SPLIT3_TOTAL 1638400

typedef __attribute__((ext_vector_type(8))) short short8;
typedef __attribute__((ext_vector_type(4))) float floatx4;

// ---------------- bf16 split helpers (RNE) ----------------
__device__ inline unsigned short bf16_rne(float f) {
    unsigned int u = __float_as_uint(f);
    u += 0x7fffu + ((u >> 16) & 1u);
    return (unsigned short)(u >> 16);
}
__device__ inline float bf16_to_f(unsigned short h) {
    return __uint_as_float(((unsigned int)h) << 16);
}
__device__ inline void write_hilo(float v, unsigned short* ph, unsigned short* pl) {
    unsigned short h = bf16_rne(v);
    *ph = h;
    *pl = bf16_rne(v - bf16_to_f(h));
}

// ---------------- native-transcendental helpers ----------------
__device__ inline float fexp(float x)  { return __expf(x); }
__device__ inline float fsilu(float x) { return x * __frcp_rn(1.f + __expf(-x)); }
__device__ inline float fsoftplus(float x) {
    return fmaxf(x, 0.f) + __logf(1.f + __expf(-fabsf(x)));
}

__device__ inline void gload16(const unsigned short* g, unsigned short* l) {
    __builtin_amdgcn_global_load_lds((const __attribute__((address_space(1))) void*)g,
                                     (__attribute__((address_space(3))) void*)l,
                                     16, 0, 0);
}

// ---------------------------------------------------------------------------
// Tiled Gaussian smoothing (sliding register window)
// ---------------------------------------------------------------------------
__global__ __launch_bounds__(256) void smooth_kernel(const float* __restrict__ X,
                                                     unsigned short* __restrict__ XSh,
                                                     unsigned short* __restrict__ XSl)
{
    int d = threadIdx.x;
    int b = blockIdx.y;
    int t0 = blockIdx.x * TT;

    float w[20]; float sum = 0.f;
    #pragma unroll
    for (int j = 0; j < 20; j++) {
        float t = ((float)j - 9.5f) * 0.5f;
        w[j] = __expf(-0.5f * t * t);
        sum += w[j];
    }
    float inv = __frcp_rn(sum);

    const float* Xb = X + ((size_t)b * TLEN) * NDIM + d;
    float win[20];
    #pragma unroll
    for (int j = 0; j < 20; j++) {
        int t2 = t0 - 9 + j;
        win[j] = (t2 >= 0 && t2 < TLEN) ? Xb[(size_t)t2 * NDIM] : 0.f;
    }
    size_t obase = ((size_t)b * TLEN + t0) * NDIM + d;
    #pragma unroll
    for (int i = 0; i < TT; i++) {
        float acc = 0.f;
        #pragma unroll
        for (int j = 0; j < 20; j++) acc = fmaf(win[j], w[j], acc);
        write_hilo(acc * inv, XSh + obase + (size_t)i * NDIM, XSl + obase + (size_t)i * NDIM);
        #pragma unroll
        for (int j = 0; j < 19; j++) win[j] = win[j + 1];
        int t2 = t0 + i + 11;
        win[19] = (t2 < TLEN) ? Xb[(size_t)t2 * NDIM] : 0.f;
    }
}

// ---------------------------------------------------------------------------
// Repack day weights for the 8 selected days (transposed, hi/lo) + bias
// ---------------------------------------------------------------------------
__global__ __launch_bounds__(256) void repack_day(const float* __restrict__ day_w,
                                                  const float* __restrict__ day_b,
                                                  const int*   __restrict__ dayIdx,
                                                  unsigned short* __restrict__ Wh,
                                                  unsigned short* __restrict__ Wl,
                                                  float* __restrict__ biasbuf)
{
    int idx = blockIdx.x * 256 + threadIdx.x;   // 8*65536
    if (idx >= 8 * 65536) return;
    int b = idx >> 16;
    int rem = idx & 65535;
    int n = rem >> 8, k = rem & 255;
    int day = dayIdx[b];
    float v = day_w[(size_t)day * 65536 + (size_t)k * 256 + n];
    write_hilo(v, Wh + idx, Wl + idx);
    if (rem < 256) biasbuf[b * 256 + rem] = day_b[(size_t)day * 256 + rem];
}

// ---------------------------------------------------------------------------
// Repack lin_in_w with K reordered as kk' = r*256 + dd (hi/lo)
// ---------------------------------------------------------------------------
__global__ __launch_bounds__(256) void repack_linin(const float* __restrict__ W,
                                                    unsigned short* __restrict__ Wh,
                                                    unsigned short* __restrict__ Wl)
{
    int idx = blockIdx.x * 256 + threadIdx.x;   // 512*3584
    if (idx >= 512 * 3584) return;
    int o = idx / 3584;
    int kk = idx - o * 3584;
    int r = kk >> 8, dd = kk & 255;
    float v = W[(size_t)o * 3584 + dd * 14 + r];
    write_hilo(v, Wh + idx, Wl + idx);
}

// ---------------------------------------------------------------------------
// Per-layer fused weight split: in_proj | x_proj | out_proj -> hi/lo scratch
// ---------------------------------------------------------------------------
__global__ __launch_bounds__(256) void split3_kernel(const float* __restrict__ ipw,
                                                     const float* __restrict__ xpw,
                                                     const float* __restrict__ opw,
                                                     unsigned short* __restrict__ Wh,
                                                     unsigned short* __restrict__ Wl)
{
    int i = blockIdx.x * 256 + threadIdx.x;
    if (i >= SPLIT3_TOTAL) return;
    float v;
    if (i < OFF_XP)      v = ipw[i];
    else if (i < OFF_OP) v = xpw[i - OFF_XP];
    else                 v = opw[i - OFF_OP];
    write_hilo(v, Wh + i, Wl + i);
}

// ---------------------------------------------------------------------------
// Generic fp32 -> bf16 hi/lo conversion (fc weights)
// ---------------------------------------------------------------------------
__global__ __launch_bounds__(256) void convw_kernel(const float* __restrict__ src,
                                                    unsigned short* __restrict__ dh,
                                                    unsigned short* __restrict__ dl,
                                                    int n)
{
    int i = blockIdx.x * 256 + threadIdx.x;
    if (i < n) write_hilo(src[i], dh + i, dl + i);
}

// ---------------------------------------------------------------------------
// Fused bf16x3 MFMA GEMM, BK=64, 96 MFMA per barrier, 4 hi/lo LDS tiles.
// LDS 64KB (4 x 16KB). XOR swizzle (chunk ^ row&7) — measured 0 conflicts.
// ---------------------------------------------------------------------------
template<int WF32, int WHL, int BIASF, int ACT, int AMAP, int SPLIT>
__global__ __launch_bounds__(256, 2) void mfma_gemm3(
    const unsigned short* __restrict__ Ah, const unsigned short* __restrict__ Al, int lda,
    const unsigned short* __restrict__ Bh, const unsigned short* __restrict__ Bl, int ldb,
    float* __restrict__ Cf, unsigned short* __restrict__ Ch, unsigned short* __restrict__ Cl,
    int ldc, const float* __restrict__ bias, int M, int N, int K, int Kc)
{
    __shared__ __align__(16) unsigned short AsH[128 * 64];
    __shared__ __align__(16) unsigned short AsL[128 * 64];
    __shared__ __align__(16) unsigned short BsH[128 * 64];
    __shared__ __align__(16) unsigned short BsL[128 * 64];
    const int tid  = threadIdx.x;
    const int wave = tid >> 6, lane = tid & 63;
    const int wm = wave & 1, wn = wave >> 1;
    const int mr = lane & 15, qh = lane >> 4;
    const int row0 = blockIdx.x * 128, col0 = blockIdx.y * 128;

    if (AMAP == 2) {
        int bb = row0 >> 11;
        Bh += (size_t)bb * 65536; Bl += (size_t)bb * 65536; bias += bb * 256;
    }

    int k0 = 0, kend = K;
    if (SPLIT) {
        k0 = blockIdx.z * Kc;
        kend = min(K, k0 + Kc);
        Cf += (size_t)blockIdx.z * (size_t)M * ldc;
    }

    size_t aoff[4], boff[4];
    int ldst[4];
    #pragma unroll
    for (int i2 = 0; i2 < 4; i2++) {
        int ch = wave * 256 + i2 * 64 + lane;
        int ar = ch >> 3, ap = ch & 7;
        int ak = (ap ^ (ar & 7)) * 8;
        ldst[i2] = ch * 8;
        int grow = row0 + ar;
        size_t base;
        if (AMAP == 0) {
            base = (size_t)min(grow, M - 1) * lda + ak;
        } else if (AMAP == 1) {
            int m = min(grow, M - 1);
            int b = m / 497, l = m - b * 497;
            base = ((size_t)(b * 2000 + l * 4) << 8) + ak;
        } else {
            int b = grow >> 11, t = min(grow & 2047, 1999);
            base = ((size_t)(b * 2000 + t) << 8) + ak;
        }
        aoff[i2] = base;
        boff[i2] = (size_t)min(col0 + ar, N - 1) * ldb + ak;
    }

    floatx4 acc[4][4];
    #pragma unroll
    for (int i = 0; i < 4; i++)
        #pragma unroll
        for (int j = 0; j < 4; j++) acc[i][j] = (floatx4){0.f, 0.f, 0.f, 0.f};

    for (int kt = k0; kt < kend; kt += 64) {
        __syncthreads();
        #pragma unroll
        for (int i2 = 0; i2 < 4; i2++) {
            gload16(Ah + aoff[i2] + kt, &AsH[ldst[i2]]);
            gload16(Al + aoff[i2] + kt, &AsL[ldst[i2]]);
            gload16(Bh + boff[i2] + kt, &BsH[ldst[i2]]);
            gload16(Bl + boff[i2] + kt, &BsL[ldst[i2]]);
        }
        __syncthreads();

        #pragma unroll
        for (int s = 0; s < 2; s++) {
            short8 ah4[4], al4[4], bh4[4], bl4[4];
            #pragma unroll
            for (int i = 0; i < 4; i++) {
                int ro = wm * 64 + i * 16 + mr;
                int ao = ro * 64 + (((s * 4 + qh) ^ (mr & 7)) * 8);
                ah4[i] = *(const short8*)&AsH[ao];
                al4[i] = *(const short8*)&AsL[ao];
            }
            #pragma unroll
            for (int j = 0; j < 4; j++) {
                int ro = wn * 64 + j * 16 + mr;
                int bo = ro * 64 + (((s * 4 + qh) ^ (mr & 7)) * 8);
                bh4[j] = *(const short8*)&BsH[bo];
                bl4[j] = *(const short8*)&BsL[bo];
            }
            #pragma unroll
            for (int i = 0; i < 4; i++)
                #pragma unroll
                for (int j = 0; j < 4; j++)
                    acc[i][j] = __builtin_amdgcn_mfma_f32_16x16x32_bf16(ah4[i], bh4[j], acc[i][j], 0, 0, 0);
            #pragma unroll
            for (int i = 0; i < 4; i++)
                #pragma unroll
                for (int j = 0; j < 4; j++)
                    acc[i][j] = __builtin_amdgcn_mfma_f32_16x16x32_bf16(ah4[i], bl4[j], acc[i][j], 0, 0, 0);
            #pragma unroll
            for (int i = 0; i < 4; i++)
                #pragma unroll
                for (int j = 0; j < 4; j++)
                    acc[i][j] = __builtin_amdgcn_mfma_f32_16x16x32_bf16(al4[i], bh4[j], acc[i][j], 0, 0, 0);
        }
    }

    const int rq = qh * 4;
    #pragma unroll
    for (int i = 0; i < 4; i++) {
        #pragma unroll
        for (int j = 0; j < 4; j++) {
            int colg = col0 + wn * 64 + j * 16 + mr;
            if (colg >= N) continue;
            #pragma unroll
            for (int r = 0; r < 4; r++) {
                int rowg = row0 + wm * 64 + i * 16 + rq + r;
                if (SPLIT) {
                    if (rowg < M) Cf[(size_t)rowg * ldc + colg] = acc[i][j][r];
                    continue;
                }
                int orow; bool rok;
                if (AMAP == 2) {
                    int bb = rowg >> 11, t = rowg & 2047;
                    rok = (t < 2000);
                    orow = bb * 2000 + t;
                } else { rok = (rowg < M); orow = rowg; }
                if (!rok) continue;
                float v = acc[i][j][r];
                if (BIASF) v += bias[colg];
                if (ACT == 1) v = fmaxf(v, 0.f) + log1pf(expf(-fabsf(v)));
                if (ACT == 2) v = v / (1.f + fabsf(v));
                size_t oidx = (size_t)orow * ldc + colg;
                if (WF32) Cf[oidx] = v;
                if (WHL)  write_hilo(v, Ch + oidx, Cl + oidx);
            }
        }
    }
}

// ---------------------------------------------------------------------------
// Split-K reduction + bias/act + fp32/hilo writes
// ---------------------------------------------------------------------------
template<int WF32, int WHL, int BIASF, int ACT>
__global__ __launch_bounds__(256) void reduce_k(const float* __restrict__ Cp,
                                                size_t pstride, int nsplit,
                                                float* __restrict__ Cf,
                                                unsigned short* __restrict__ Ch,
                                                unsigned short* __restrict__ Cl,
                                                const float* __restrict__ bias,
                                                int N, int total)
{
    int i = blockIdx.x * 256 + threadIdx.x;
    if (i >= total) return;
    float v = 0.f;
    for (int z = 0; z < nsplit; z++) v += Cp[(size_t)z * pstride + i];
    if (BIASF) v += bias[i % N];
    if (ACT == 1) v = fmaxf(v, 0.f) + log1pf(expf(-fabsf(v)));
    if (WF32) Cf[i] = v;
    if (WHL)  write_hilo(v, Ch + i, Cl + i);
}

// ---------------------------------------------------------------------------
// Causal depthwise conv (k=4) + bias + SiLU -> hi/lo only (x_proj A operand)
// ---------------------------------------------------------------------------
__global__ __launch_bounds__(256) void conv_silu_kernel(const float* __restrict__ XZ,
                                                        const float* __restrict__ cw,
                                                        const float* __restrict__ cb,
                                                        unsigned short* __restrict__ XCh,
                                                        unsigned short* __restrict__ XCl)
{
    int idx = blockIdx.x * 256 + threadIdx.x;   // 3976*1024
    if (idx >= MROWS * DINNER) return;
    int row = idx >> 10, c = idx & 1023;
    unsigned b = (unsigned)row / 497u;
    int l = row - (int)b * 497;
    float acc = cb[c];
    #pragma unroll
    for (int j = 0; j < 4; j++) {
        int lj = l - 3 + j;
        if (lj >= 0) acc += XZ[(size_t)(row - 3 + j) * 2048 + c] * cw[c * 4 + j];
    }
    write_hilo(fsilu(acc), XCh + idx, XCl + idx);
}

// ---------------------------------------------------------------------------
// Scan phase 1: fused split-K reduce during staging (8 partials), dt-dot +
// softplus (stored to DV) + conv/SiLU + local scan.
// ---------------------------------------------------------------------------
__global__ __launch_bounds__(256) void scan_part1(const float* __restrict__ XZ,
                                                  const float* __restrict__ PART,
                                                  const float* __restrict__ dtw,
                                                  const float* __restrict__ dtb,
                                                  const float* __restrict__ cw,
                                                  const float* __restrict__ cb,
                                                  const float* __restrict__ Alog,
                                                  float* __restrict__ DV,
                                                  float* __restrict__ SEnd,
                                                  float* __restrict__ Pp)
{
    __shared__ float sR[CSZ][64];
    int tid = threadIdx.x;
    int bid = blockIdx.x;
    int c = bid % NCH; int r = bid / NCH;
    int db = r & 3, b = r >> 2;
    int d = db * 256 + tid;
    int t0 = c * CSZ;
    int tcnt = min(CSZ, LOUT - t0);
    int rowbase = b * LOUT + t0;

    int li = tid >> 4, lj = (tid & 15) * 4;
    #pragma unroll
    for (int g = 0; g < 2; g++) {
        int rr = li + g * 16;
        if (rr < tcnt) {
            float a0 = 0.f, a1 = 0.f, a2 = 0.f, a3 = 0.f;
            size_t eb = (size_t)(rowbase + rr) * 64 + lj;
            #pragma unroll
            for (int z = 0; z < 8; z++) {
                float4 v = *(const float4*)(PART + (size_t)z * PSTRIDE + eb);
                a0 += v.x; a1 += v.y; a2 += v.z; a3 += v.w;
            }
            sR[rr][lj] = a0; sR[rr][lj+1] = a1; sR[rr][lj+2] = a2; sR[rr][lj+3] = a3;
        }
    }
    __syncthreads();

    float w[32];
    #pragma unroll
    for (int k = 0; k < 8; k++)
        *(float4*)&w[k * 4] = *(const float4*)(dtw + (size_t)d * 32 + k * 4);
    float dtbv = dtb[d];
    float4 cwv = *(const float4*)(cw + (size_t)d * 4);
    float cbv = cb[d];

    float a[DSTATE], cum[DSTATE], s[DSTATE];
    #pragma unroll
    for (int n = 0; n < DSTATE; n++) {
        a[n] = -fexp(Alog[(size_t)d * DSTATE + n]);
        cum[n] = 1.f; s[n] = 0.f;
    }

    const float* Xp = XZ + d;   // x half, stride 2048
    float xm1 = 0.f, xm2 = 0.f, xm3 = 0.f;
    if (t0 >= 1) xm1 = Xp[(size_t)(rowbase - 1) * 2048];
    if (t0 >= 2) xm2 = Xp[(size_t)(rowbase - 2) * 2048];
    if (t0 >= 3) xm3 = Xp[(size_t)(rowbase - 3) * 2048];
    float xr = Xp[(size_t)rowbase * 2048];

    for (int tt = 0; tt < tcnt; tt++) {
        float xr_n = (tt + 1 < tcnt) ? Xp[(size_t)(rowbase + tt + 1) * 2048] : 0.f;
        float d0 = dtbv, d1 = 0.f, d2 = 0.f, d3 = 0.f;
        #pragma unroll
        for (int k = 0; k < 8; k++) {
            d0 = fmaf(sR[tt][4*k+0], w[4*k+0], d0);
            d1 = fmaf(sR[tt][4*k+1], w[4*k+1], d1);
            d2 = fmaf(sR[tt][4*k+2], w[4*k+2], d2);
            d3 = fmaf(sR[tt][4*k+3], w[4*k+3], d3);
        }
        float dot = (d0 + d1) + (d2 + d3);
        float dv = fsoftplus(dot);
        DV[(size_t)(rowbase + tt) * DINNER + d] = dv;
        float pre = cbv + cwv.x * xm3 + cwv.y * xm2 + cwv.z * xm1 + cwv.w * xr;
        float xv = fsilu(pre);
        float dx = dv * xv;
        #pragma unroll
        for (int n = 0; n < DSTATE; n++) {
            float e = fexp(dv * a[n]);
            cum[n] *= e;
            s[n] = fmaf(e, s[n], dx * sR[tt][32 + n]);
        }
        xm3 = xm2; xm2 = xm1; xm1 = xr; xr = xr_n;
    }
    size_t base = ((size_t)(c * 8 + b) * 16) * 1024 + d;
    #pragma unroll
    for (int n = 0; n < DSTATE; n++) {
        SEnd[base + (size_t)n * 1024] = s[n];
        Pp[base + (size_t)n * 1024]   = cum[n];
    }
}

// ---------------------------------------------------------------------------
// Scan phase 2: bulk-preloaded combine; SIn written in place over Pp.
// ---------------------------------------------------------------------------
__global__ __launch_bounds__(256) void scan_part2(const float* __restrict__ SEnd,
                                                  float* __restrict__ PS)
{
    int tid = threadIdx.x;
    int bid = blockIdx.x;           // 512 = 8b * 16n * 4db
    int db = bid & 3, n = (bid >> 2) & 15, b = bid >> 6;
    int d = db * 256 + tid;
    size_t base = ((size_t)(b * 16 + n)) * 1024 + d;
    float pc[NCH], se[NCH];
    #pragma unroll
    for (int c = 0; c < NCH; c++) {
        size_t idx = base + (size_t)c * (8 * 16 * 1024);
        pc[c] = PS[idx];
        se[c] = SEnd[idx];
    }
    float s = 0.f;
    #pragma unroll
    for (int c = 0; c < NCH; c++) {
        size_t idx = base + (size_t)c * (8 * 16 * 1024);
        PS[idx] = s;
        s = fmaf(pc[c], s, se[c]);
    }
}

// ---------------------------------------------------------------------------
// Scan phase 3: fused split-K reduce for B/C cols, dv loaded from DV,
// conv recomputed, seeded state, gated y out (hilo).
// ---------------------------------------------------------------------------
__global__ __launch_bounds__(256) void scan_part3(const float* __restrict__ XZ,
                                                  const float* __restrict__ PART,
                                                  const float* __restrict__ DV,
                                                  const float* __restrict__ cw,
                                                  const float* __restrict__ cb,
                                                  const float* __restrict__ Alog,
                                                  const float* __restrict__ Dp,
                                                  const float* __restrict__ SIn,
                                                  unsigned short* __restrict__ Yh,
                                                  unsigned short* __restrict__ Yl)
{
    __shared__ float sR[CSZ][32];
    int tid = threadIdx.x;
    int bid = blockIdx.x;
    int c = bid % NCH; int r = bid / NCH;
    int db = r & 3, b = r >> 2;
    int d = db * 256 + tid;
    int t0 = c * CSZ;
    int tcnt = min(CSZ, LOUT - t0);
    int rowbase = b * LOUT + t0;

    int li = tid >> 3, lj = (tid & 7) * 4;
    if (li < tcnt) {
        float a0 = 0.f, a1 = 0.f, a2 = 0.f, a3 = 0.f;
        size_t eb = (size_t)(rowbase + li) * 64 + 32 + lj;
        #pragma unroll
        for (int z = 0; z < 8; z++) {
            float4 v = *(const float4*)(PART + (size_t)z * PSTRIDE + eb);
            a0 += v.x; a1 += v.y; a2 += v.z; a3 += v.w;
        }
        sR[li][lj] = a0; sR[li][lj+1] = a1; sR[li][lj+2] = a2; sR[li][lj+3] = a3;
    }
    __syncthreads();

    float4 cwv = *(const float4*)(cw + (size_t)d * 4);
    float cbv = cb[d];
    float dD = Dp[d];

    float a[DSTATE], s[DSTATE];
    size_t base = ((size_t)(c * 8 + b) * 16) * 1024 + d;
    #pragma unroll
    for (int n = 0; n < DSTATE; n++) {
        a[n] = -fexp(Alog[(size_t)d * DSTATE + n]);
        s[n] = SIn[base + (size_t)n * 1024];
    }

    const float* Xp = XZ + d;          // x half
    const float* Zp = XZ + 1024 + d;   // z half
    const float* Vp = DV + d;
    float xm1 = 0.f, xm2 = 0.f, xm3 = 0.f;
    if (t0 >= 1) xm1 = Xp[(size_t)(rowbase - 1) * 2048];
    if (t0 >= 2) xm2 = Xp[(size_t)(rowbase - 2) * 2048];
    if (t0 >= 3) xm3 = Xp[(size_t)(rowbase - 3) * 2048];
    float xr = Xp[(size_t)rowbase * 2048];
    float zr = Zp[(size_t)rowbase * 2048];
    float dv = Vp[(size_t)rowbase * 1024];

    for (int tt = 0; tt < tcnt; tt++) {
        float xr_n = 0.f, zr_n = 0.f, dv_n = 0.f;
        if (tt + 1 < tcnt) {
            xr_n = Xp[(size_t)(rowbase + tt + 1) * 2048];
            zr_n = Zp[(size_t)(rowbase + tt + 1) * 2048];
            dv_n = Vp[(size_t)(rowbase + tt + 1) * 1024];
        }
        float pre = cbv + cwv.x * xm3 + cwv.y * xm2 + cwv.z * xm1 + cwv.w * xr;
        float xv = fsilu(pre);
        float dx = dv * xv;
        float y = 0.f;
        #pragma unroll
        for (int n = 0; n < DSTATE; n++) {
            float e = fexp(dv * a[n]);
            s[n] = fmaf(e, s[n], dx * sR[tt][n]);
            y = fmaf(s[n], sR[tt][DSTATE + n], y);
        }
        float g = fsilu(zr);
        float yv = (y + xv * dD) * g;
        size_t row = (size_t)(rowbase + tt);
        write_hilo(yv, Yh + row * DINNER + d, Yl + row * DINNER + d);
        xm3 = xm2; xm2 = xm1; xm1 = xr; xr = xr_n; zr = zr_n; dv = dv_n;
    }
}

// ---------------------------------------------------------------------------
extern "C" void kernel_launch(void* const* d_in, const int* in_sizes, int n_in,
                              void* d_out, int out_size, void* d_ws, size_t ws_size,
                              hipStream_t stream)
{
    const float* neuralInput = (const float*)d_in[0];
    const int*   dayIdx      = (const int*)  d_in[1];
    const float* day_w       = (const float*)d_in[2];
    const float* day_b       = (const float*)d_in[3];
    const float* lin_in_w    = (const float*)d_in[4];
    const float* lin_in_b    = (const float*)d_in[5];
    const float* in_proj_w   = (const float*)d_in[6];
    const float* conv_w      = (const float*)d_in[7];
    const float* conv_b      = (const float*)d_in[8];
    const float* x_proj_w    = (const float*)d_in[9];
    const float* dt_w        = (const float*)d_in[10];
    const float* dt_b        = (const float*)d_in[11];
    const float* A_log       = (const float*)d_in[12];
    const float* D_param     = (const float*)d_in[13];
    const float* out_proj_w  = (const float*)d_in[14];
    const float* fc_w        = (const float*)d_in[15];
    const float* fc_b        = (const float*)d_in[16];
    float* out = (float*)d_out;

    // ---------------- workspace layout (floats) ----------------
    float* p = (float*)d_ws;
    float* xz   = p; p += (size_t)MROWS * 2048;           // 8,142,848
    float* xcv  = p; p += (size_t)MROWS * DINNER;         // 4,071,424 (Pp/SIn region)
    float* dl   = p; p += (size_t)MROWS * DINNER;         // 4,071,424 (x_proj partials / fc partials)
    float* xdbc = p; p += (size_t)MROWS * 64;             //   254,464 (unused; layout stability)
    unsigned short* Hh = (unsigned short*)p;              // h hi/lo (3976x512)
    unsigned short* Hl = Hh + (size_t)MROWS * DMODEL;
    p += (size_t)MROWS * DMODEL;
    unsigned short* XSh = (unsigned short*)p;             // smooth out hi/lo
    unsigned short* XSl = XSh + (size_t)BATCH * TLEN * NDIM;
    p += (size_t)BATCH * TLEN * NDIM;
    unsigned short* XCh = XSh;                            // alias: conv out hi/lo
    unsigned short* XCl = XCh + (size_t)MROWS * DINNER;
    float* DVb = (float*)XSh;                             // alias: dv store (dead XChl region,
                                                          // 4,071,424 <= 4,096,000)
    float* xdreg = p;                                     // day-out region (4,096,000)
    unsigned short* XDh = (unsigned short*)p;
    unsigned short* XDl = XDh + (size_t)BATCH * TLEN * NDIM;
    p += (size_t)BATCH * TLEN * NDIM;
    unsigned short* Yh = XDh;                             // alias: scan out hi/lo
    unsigned short* Yl = Yh + (size_t)MROWS * DINNER;
    float* SEnd = xdreg;                                  // 25*8*16*1024 = 3,276,800
    float* Pp   = xcv;                                    // 3,276,800 <= 4,071,424
    float* SIn  = Pp;                                     // in-place after scan_part2
    unsigned short* Wh = (unsigned short*)p;              // weight hi/lo scratch
    unsigned short* Wl = Wh + 1835008;
    p += 1835008;                                         // 1,835,008 floats
    float* daybias = p; p += 2048;
    float* bigpart = xz;      // lin_in / out_proj split-K partials: 4 x 3976 x 512
    float* smlpart = dl;      // x_proj partials (8 x 3976 x 64); fc partials (4 x 3976 x 41)
    (void)xdbc;

    // 1. smooth -> XShl (tiled sliding-window)
    smooth_kernel<<<dim3(TLEN/TT, BATCH), 256, 0, stream>>>(neuralInput, XSh, XSl);
    // 2. day weights repack (hi/lo) + day GEMM (softsign) -> XDhl
    repack_day<<<dim3((8*65536)/256), 256, 0, stream>>>(day_w, day_b, dayIdx, Wh, Wl, daybias);
    mfma_gemm3<0,1,1,2,2,0><<<dim3(128, 2), 256, 0, stream>>>(
        XSh, XSl, 256, Wh, Wl, 256, nullptr, XDh, XDl, 256, daybias, 16000, 256, 256, 0);
    // 3. lin_in repack (hi/lo) + split-K GEMM -> Hhl
    repack_linin<<<dim3((512*3584)/256), 256, 0, stream>>>(lin_in_w, Wh, Wl);
    mfma_gemm3<0,0,0,0,1,1><<<dim3(32, 4, 4), 256, 0, stream>>>(
        XDh, XDl, 0, Wh, Wl, 3584, bigpart, nullptr, nullptr, DMODEL, nullptr,
        MROWS, DMODEL, 3584, 896);
    reduce_k<0,1,1,0><<<dim3((MROWS*DMODEL)/256), 256, 0, stream>>>(
        bigpart, (size_t)MROWS*DMODEL, 4, nullptr, Hh, Hl, lin_in_b, DMODEL, MROWS*DMODEL);

    for (int l = 0; l < LAYERS; l++) {
        const float* ipw = in_proj_w  + (size_t)l * 2048 * DMODEL;
        const float* cwl = conv_w     + (size_t)l * DINNER * 4;
        const float* cbl = conv_b     + (size_t)l * DINNER;
        const float* xpw = x_proj_w   + (size_t)l * 64 * DINNER;
        const float* dtw = dt_w       + (size_t)l * DINNER * DTRANK;
        const float* dtb = dt_b       + (size_t)l * DINNER;
        const float* alg = A_log      + (size_t)l * DINNER * DSTATE;
        const float* dpl = D_param    + (size_t)l * DINNER;
        const float* opw = out_proj_w + (size_t)l * DMODEL * DINNER;

        // one fused weight split per layer (in_proj | x_proj | out_proj)
        split3_kernel<<<dim3((SPLIT3_TOTAL+255)/256), 256, 0, stream>>>(ipw, xpw, opw, Wh, Wl);
        // in_proj: (3976x512)@(2048x512)^T -> xz fp32
        mfma_gemm3<1,0,0,0,0,0><<<dim3(32, 16), 256, 0, stream>>>(
            Hh, Hl, DMODEL, Wh + OFF_IP, Wl + OFF_IP, DMODEL, xz, nullptr, nullptr, 2048,
            nullptr, MROWS, 2048, DMODEL, 0);
        // conv + silu -> XChl (hilo only)
        conv_silu_kernel<<<dim3((MROWS*DINNER)/256), 256, 0, stream>>>(xz, cwl, cbl, XCh, XCl);
        // x_proj: split-K 8 -> smlpart (reduction fused into scan staging)
        mfma_gemm3<0,0,0,0,0,1><<<dim3(32, 1, 8), 256, 0, stream>>>(
            XCh, XCl, DINNER, Wh + OFF_XP, Wl + OFF_XP, DINNER, smlpart, nullptr, nullptr, 64,
            nullptr, MROWS, 64, DINNER, 128);
        // chunked scan (fused reduce + dt + conv + gate) -> Yhl ; dv cached in DVb
        scan_part1<<<dim3(8*4*NCH), 256, 0, stream>>>(xz, smlpart, dtw, dtb, cwl, cbl, alg,
                                                      DVb, SEnd, Pp);
        scan_part2<<<dim3(512), 256, 0, stream>>>(SEnd, Pp);
        scan_part3<<<dim3(8*4*NCH), 256, 0, stream>>>(xz, smlpart, DVb, cwl, cbl, alg,
                                                      dpl, SIn, Yh, Yl);
        // out_proj: split-K 4 -> Hhl
        mfma_gemm3<0,0,0,0,0,1><<<dim3(32, 4, 4), 256, 0, stream>>>(
            Yh, Yl, DINNER, Wh + OFF_OP, Wl + OFF_OP, DINNER, bigpart, nullptr, nullptr,
            DMODEL, nullptr, MROWS, DMODEL, DINNER, 256);
        reduce_k<0,1,0,0><<<dim3((MROWS*DMODEL)/256), 256, 0, stream>>>(
            bigpart, (size_t)MROWS*DMODEL, 4, nullptr, Hh, Hl, nullptr, DMODEL, MROWS*DMODEL);
    }

    // fc: split + split-K 4 -> out (3976 x 41) fp32 + bias
    convw_kernel<<<dim3((NCLS*DMODEL+255)/256), 256, 0, stream>>>(fc_w, Wh, Wl, NCLS*DMODEL);
    mfma_gemm3<0,0,0,0,0,1><<<dim3(32, 1, 4), 256, 0, stream>>>(
        Hh, Hl, DMODEL, Wh, Wl, DMODEL, smlpart, nullptr, nullptr, NCLS, nullptr,
        MROWS, NCLS, DMODEL, 128);
    reduce_k<1,0,1,0><<<dim3((MROWS*NCLS+255)/256), 256, 0, stream>>>(
        smlpart, (size_t)MROWS*NCLS, 4, out, nullptr, nullptr, fc_b, NCLS, MROWS*NCLS);
}